// Round 7
// baseline (383.036 us; speedup 1.0000x reference)
//
#include <hip/hip_runtime.h>
#include <hip/hip_bf16.h>

#define N_NODES 32768
#define E_EDGES 1048576
#define HID 128
#define G_GRAPHS 128
#define NPG 256
#define NH 8
#define DH 16
#define EPS 1e-5f
#define CHUNK 4096
#define BCAP 8192

typedef __attribute__((ext_vector_type(4))) float f32x4;
typedef __attribute__((ext_vector_type(4))) short bf16x4;

static __device__ __forceinline__ unsigned short bfbits(float f) {
    return __builtin_bit_cast(unsigned short, __float2bfloat16(f));
}
static __device__ __forceinline__ float bf2f(unsigned short u) {
    return __builtin_bit_cast(float, (unsigned)u << 16);
}
static __device__ __forceinline__ float rdlanef(float v, int l) {
    return __builtin_bit_cast(float, __builtin_amdgcn_readlane(__builtin_bit_cast(int, v), l));
}

// ---------------- helpers ----------------
__device__ __forceinline__ void ln_stats128(float v, float& mean, float& istd, float* red) {
    float s = v, s2 = v * v;
#pragma unroll
    for (int off = 32; off; off >>= 1) { s += __shfl_xor(s, off); s2 += __shfl_xor(s2, off); }
    int w = threadIdx.x >> 6;
    if ((threadIdx.x & 63) == 0) { red[w * 2] = s; red[w * 2 + 1] = s2; }
    __syncthreads();
    float ts = red[0] + red[2], ts2 = red[1] + red[3];
    mean = ts * (1.f / 128.f);
    float var = ts2 * (1.f / 128.f) - mean * mean;
    istd = rsqrtf(var + EPS);
    __syncthreads();
}

// 256-thread block, 128 live values (threads >=128 pass v=0)
__device__ __forceinline__ void ln_stats256(float v, float& mean, float& istd, float* red8) {
    float s = v, s2 = v * v;
#pragma unroll
    for (int off = 32; off; off >>= 1) { s += __shfl_xor(s, off); s2 += __shfl_xor(s2, off); }
    int w = threadIdx.x >> 6;
    if ((threadIdx.x & 63) == 0) { red8[w * 2] = s; red8[w * 2 + 1] = s2; }
    __syncthreads();
    float ts = red8[0] + red8[2] + red8[4] + red8[6];
    float ts2 = red8[1] + red8[3] + red8[5] + red8[7];
    mean = ts * (1.f / 128.f);
    float var = ts2 * (1.f / 128.f) - mean * mean;
    istd = rsqrtf(var + EPS);
    __syncthreads();
}

// ---------------- CSR build: bucketed counting sort ----------------
__global__ __launch_bounds__(256) void bucket_count(const int* __restrict__ dst,
                                                    int* __restrict__ bucket_cnt) {
    __shared__ int bcnt[256];
    int tid = threadIdx.x;
    bcnt[tid] = 0;
    __syncthreads();
    int base = blockIdx.x * CHUNK;
#pragma unroll
    for (int j = 0; j < 16; j++) {
        int d = dst[base + j * 256 + tid];
        atomicAdd(&bcnt[d >> 7], 1);
    }
    __syncthreads();
    atomicAdd(&bucket_cnt[tid], bcnt[tid]);
}

__global__ __launch_bounds__(256) void scan_buckets(const int* __restrict__ bucket_cnt,
                                                    int* __restrict__ bucket_base,
                                                    int* __restrict__ bucket_fill) {
    __shared__ int sc[256];
    int t = threadIdx.x;
    int c = bucket_cnt[t];
    sc[t] = c;
    __syncthreads();
    for (int off = 1; off < 256; off <<= 1) {
        int v = (t >= off) ? sc[t - off] : 0;
        __syncthreads();
        sc[t] += v;
        __syncthreads();
    }
    int ex = sc[t] - c;
    bucket_base[t] = ex;
    bucket_fill[t] = ex;
    if (t == 255) bucket_base[256] = sc[255];
}

__global__ __launch_bounds__(256) void bucket_scatter(const int* __restrict__ src,
                                                      const int* __restrict__ dst,
                                                      int* __restrict__ bucket_fill,
                                                      int* __restrict__ packed) {
    __shared__ int bcnt[256];
    __shared__ int lsc[256];
    __shared__ int delta[256];
    __shared__ int sorted[CHUNK];
    int tid = threadIdx.x;
    int base = blockIdx.x * CHUNK;
    int pk[16], bk[16], rk[16];
    bcnt[tid] = 0;
    __syncthreads();
#pragma unroll
    for (int j = 0; j < 16; j++) {
        int e = base + j * 256 + tid;
        int d = dst[e], s = src[e];
        pk[j] = (d << 15) | s;
        bk[j] = d >> 7;
    }
#pragma unroll
    for (int j = 0; j < 16; j++) rk[j] = atomicAdd(&bcnt[bk[j]], 1);
    __syncthreads();
    int cnt_t = bcnt[tid];
    lsc[tid] = cnt_t;
    __syncthreads();
    for (int off = 1; off < 256; off <<= 1) {
        int v = (tid >= off) ? lsc[tid - off] : 0;
        __syncthreads();
        lsc[tid] += v;
        __syncthreads();
    }
    int ls_t = lsc[tid] - cnt_t;
    __syncthreads();
    lsc[tid] = ls_t;
    int g = 0;
    if (cnt_t > 0) g = atomicAdd(&bucket_fill[tid], cnt_t);
    delta[tid] = g - ls_t;
    __syncthreads();
#pragma unroll
    for (int j = 0; j < 16; j++) sorted[lsc[bk[j]] + rk[j]] = pk[j];
    __syncthreads();
    for (int i = tid; i < CHUNK; i += 256) {
        int u = sorted[i];
        int b2 = u >> 22;
        packed[delta[b2] + i] = u;
    }
}

__global__ __launch_bounds__(256) void csr_build(const int* __restrict__ bucket_base,
                                                 const int* __restrict__ packed,
                                                 int* __restrict__ srcs,
                                                 int* __restrict__ row_ptr,
                                                 float* __restrict__ dis) {
    __shared__ int ncnt[128];
    __shared__ int sc[128];
    __shared__ int fill[128];
    __shared__ int outl[BCAP];
    int b = blockIdx.x, tid = threadIdx.x;
    int c0 = bucket_base[b], c1 = bucket_base[b + 1];
    int cnt = c1 - c0;
    if (tid < 128) ncnt[tid] = 0;
    __syncthreads();
    for (int i = tid; i < cnt; i += 256) {
        int u = packed[c0 + i];
        atomicAdd(&ncnt[(u >> 15) & 127], 1);
    }
    __syncthreads();
    int c = (tid < 128) ? ncnt[tid] : 0;
    if (tid < 128) sc[tid] = c;
    __syncthreads();
    for (int off = 1; off < 128; off <<= 1) {
        int v = (tid < 128 && tid >= off) ? sc[tid - off] : 0;
        __syncthreads();
        if (tid < 128) sc[tid] += v;
        __syncthreads();
    }
    if (tid < 128) {
        int ex = sc[tid] - c;
        fill[tid] = ex;
        int node = b * 128 + tid;
        row_ptr[node] = c0 + ex;
        dis[node] = rsqrtf((float)(c + 1));
    }
    if (b == 255 && tid == 0) row_ptr[N_NODES] = c1;
    __syncthreads();
    if (cnt <= BCAP) {
        for (int i = tid; i < cnt; i += 256) {
            int u = packed[c0 + i];
            int p = atomicAdd(&fill[(u >> 15) & 127], 1);
            outl[p] = u & 32767;
        }
        __syncthreads();
        for (int i = tid; i < cnt; i += 256) srcs[c0 + i] = outl[i];
    } else {
        for (int i = tid; i < cnt; i += 256) {
            int u = packed[c0 + i];
            int p = atomicAdd(&fill[(u >> 15) & 127], 1);
            srcs[c0 + p] = u & 32767;
        }
    }
}

// ---------------- weight prep ----------------
__global__ __launch_bounds__(256) void prep_weights(const float* __restrict__ Wc,
                                                    const float* __restrict__ Wq,
                                                    const float* __restrict__ Wk,
                                                    const float* __restrict__ Wv,
                                                    const float* __restrict__ Wo,
                                                    const float* __restrict__ bq,
                                                    const float* __restrict__ bk,
                                                    const float* __restrict__ bv,
                                                    unsigned short* __restrict__ Wpk,
                                                    float* __restrict__ bT) {
    int m = blockIdx.y;
    int idx = blockIdx.x * 256 + threadIdx.x;   // 0..16383
    int j = idx & 3, ln = (idx >> 2) & 63, kt = (idx >> 8) & 7, jt = (idx >> 11) & 7;
    int k = kt * 16 + (ln >> 4) * 4 + j;
    int col = jt * 16 + (ln & 15);
    float val;
    if (m < 3) val = Wc[m * 16384 + k * 128 + col];
    else {
        const float* W = (m == 3) ? Wq : (m == 4) ? Wk : (m == 5) ? Wv : Wo;
        val = W[col * 128 + k];
    }
    Wpk[m * 16384 + idx] = bfbits(val);
    if (m >= 3 && m < 6 && idx < 128) {
        const float* bs = (m == 3) ? bq : (m == 4) ? bk : bv;
        bT[(m - 3) * 128 + idx] = bs[idx];
    }
}

// ---------------- input projection v2: wave-per-node ----------------
__global__ __launch_bounds__(256) void input_proj(const float* __restrict__ x,
                                                  const float* __restrict__ W,
                                                  const float* __restrict__ b,
                                                  const float* __restrict__ g,
                                                  const float* __restrict__ be,
                                                  unsigned short* __restrict__ h16) {
    int wv = threadIdx.x >> 6, lane = threadIdx.x & 63;
    int n = blockIdx.x * 4 + wv;
    float xv = (lane < 15) ? x[n * 15 + lane] : 0.f;
    int c = lane * 2;
    float2 bb = *(const float2*)&b[c];
    float a0 = bb.x, a1 = bb.y;
#pragma unroll
    for (int k = 0; k < 15; k++) {
        float xk = rdlanef(xv, k);
        float2 w2 = *(const float2*)&W[k * 128 + c];
        a0 += xk * w2.x;
        a1 += xk * w2.y;
    }
    float s = a0 + a1, s2 = a0 * a0 + a1 * a1;
#pragma unroll
    for (int off = 1; off < 64; off <<= 1) { s += __shfl_xor(s, off); s2 += __shfl_xor(s2, off); }
    float mean = s * (1.f / 128.f);
    float var = s2 * (1.f / 128.f) - mean * mean;
    float is = rsqrtf(var + EPS);
    float2 gg = *(const float2*)&g[c];
    float2 be2 = *(const float2*)&be[c];
    float y0 = fmaxf((a0 - mean) * is * gg.x + be2.x, 0.f);
    float y1 = fmaxf((a1 - mean) * is * gg.y + be2.y, 0.f);
    unsigned outu = (unsigned)bfbits(y0) | ((unsigned)bfbits(y1) << 16);
    *(unsigned*)&h16[(long)n * 128 + c] = outu;
}

// ---------------- MFMA GEMM ----------------
template <int MODE>
__device__ __forceinline__ void gemm_mfma_body(const unsigned short* __restrict__ in16,
                                               const unsigned short* __restrict__ Wpk,
                                               const float* __restrict__ bias,
                                               const unsigned short* __restrict__ resid16,
                                               const float* __restrict__ gamma,
                                               const float* __restrict__ beta,
                                               unsigned short* __restrict__ out16) {
    __shared__ unsigned short Ws[16384];
    __shared__ unsigned short Hs[64][136];
    int tid = threadIdx.x;
    long base = (long)blockIdx.x * 64;
    {
        const uint4* s4 = (const uint4*)Wpk;
        uint4* d4 = (uint4*)Ws;
        for (int i = tid; i < 2048; i += 256) d4[i] = s4[i];
        const unsigned short* hsrc = in16 + base * 128;
        for (int i = tid; i < 1024; i += 256) {
            int r = i >> 4, c8 = i & 15;
            *(uint4*)&Hs[r][c8 * 8] = *(const uint4*)&hsrc[r * 128 + c8 * 8];
        }
    }
    __syncthreads();
    int wv = tid >> 6, lane = tid & 63;
    int ql = lane & 15, qg = lane >> 4;
    f32x4 acc[8];
#pragma unroll
    for (int jt = 0; jt < 8; jt++) acc[jt] = (f32x4){0.f, 0.f, 0.f, 0.f};
#pragma unroll
    for (int kt = 0; kt < 8; kt++) {
        bf16x4 af = *(const bf16x4*)&Hs[wv * 16 + ql][kt * 16 + qg * 4];
#pragma unroll
        for (int jt = 0; jt < 8; jt++) {
            bf16x4 bf = *(const bf16x4*)&Ws[((jt * 8 + kt) * 64 + lane) * 4];
            acc[jt] = __builtin_amdgcn_mfma_f32_16x16x16bf16_1k(af, bf, acc[jt], 0, 0, 0);
        }
    }
    if (MODE >= 1) {
#pragma unroll
        for (int jt = 0; jt < 8; jt++) {
            float bv = bias[jt * 16 + ql];
#pragma unroll
            for (int r = 0; r < 4; r++) acc[jt][r] += bv;
        }
    }
    if (MODE == 2) {
#pragma unroll
        for (int jt = 0; jt < 8; jt++)
#pragma unroll
            for (int r = 0; r < 4; r++)
                acc[jt][r] += bf2f(resid16[(base + wv * 16 + qg * 4 + r) * 128 + jt * 16 + ql]);
        float s[4], s2[4], mean[4], istd[4];
#pragma unroll
        for (int r = 0; r < 4; r++) { s[r] = 0.f; s2[r] = 0.f; }
#pragma unroll
        for (int jt = 0; jt < 8; jt++)
#pragma unroll
            for (int r = 0; r < 4; r++) { float v = acc[jt][r]; s[r] += v; s2[r] += v * v; }
#pragma unroll
        for (int off = 1; off < 16; off <<= 1)
#pragma unroll
            for (int r = 0; r < 4; r++) {
                s[r] += __shfl_xor(s[r], off);
                s2[r] += __shfl_xor(s2[r], off);
            }
#pragma unroll
        for (int r = 0; r < 4; r++) {
            mean[r] = s[r] * (1.f / 128.f);
            float var = s2[r] * (1.f / 128.f) - mean[r] * mean[r];
            istd[r] = rsqrtf(var + EPS);
        }
#pragma unroll
        for (int jt = 0; jt < 8; jt++) {
            float gv = gamma[jt * 16 + ql], bev = beta[jt * 16 + ql];
#pragma unroll
            for (int r = 0; r < 4; r++)
                acc[jt][r] = (acc[jt][r] - mean[r]) * istd[r] * gv + bev;
        }
    }
#pragma unroll
    for (int jt = 0; jt < 8; jt++)
#pragma unroll
        for (int r = 0; r < 4; r++)
            Hs[wv * 16 + qg * 4 + r][jt * 16 + ql] = bfbits(acc[jt][r]);
#pragma unroll
    for (int p = 0; p < 4; p++) {
        int rl = p * 4 + qg;
        uint4 v = *(const uint4*)&Hs[wv * 16 + rl][ql * 8];
        *(uint4*)&out16[(base + wv * 16 + rl) * 128 + ql * 8] = v;
    }
}

template <int MODE>
__global__ __launch_bounds__(256) void gemm_mfma(const unsigned short* __restrict__ in16,
                                                 const unsigned short* __restrict__ Wpk,
                                                 const float* __restrict__ bias,
                                                 const unsigned short* __restrict__ resid16,
                                                 const float* __restrict__ gamma,
                                                 const float* __restrict__ beta,
                                                 unsigned short* __restrict__ out16) {
    gemm_mfma_body<MODE>(in16, Wpk, bias, resid16, gamma, beta, out16);
}

__global__ __launch_bounds__(256) void gemm_qkv(const unsigned short* __restrict__ in16,
                                                const unsigned short* __restrict__ Wpk,
                                                const float* __restrict__ bT,
                                                unsigned short* __restrict__ outb) {
    int y = blockIdx.y;
    gemm_mfma_body<1>(in16, Wpk + (3 + y) * 16384, bT + y * 128, nullptr, nullptr, nullptr,
                      outb + (long)y * N_NODES * 128);
}

// ---------------- GCN aggregation v5: dual-row dwordx2 loads (2 edges / load instr) --------
__global__ __launch_bounds__(256) void gcn_agg(const unsigned short* __restrict__ hW,
                                               const int* __restrict__ row_ptr,
                                               const int* __restrict__ srcs,
                                               const float* __restrict__ dis,
                                               const float* __restrict__ bias,
                                               const float* __restrict__ gamma,
                                               const float* __restrict__ beta,
                                               unsigned short* __restrict__ h16, int with_resid) {
    int wv = threadIdx.x >> 6, lane = threadIdx.x & 63;
    int n = blockIdx.x * 4 + wv;
    int r0 = row_ptr[n], r1 = row_ptr[n + 1];
    float dn = dis[n];
    int l32 = lane & 31;
    int hi = lane >> 5;   // half-wave: 0 -> even edges, 1 -> odd edges
    float a0, a1, a2, a3;
    {
        uint2 su = *(const uint2*)&hW[(long)n * 128 + l32 * 4];
        float dh = dn * dn * 0.5f;   // both halves add it -> merge doubles back to dn*dn
        a0 = bf2f((unsigned short)(su.x & 0xffff)) * dh;
        a1 = bf2f((unsigned short)(su.x >> 16)) * dh;
        a2 = bf2f((unsigned short)(su.y & 0xffff)) * dh;
        a3 = bf2f((unsigned short)(su.y >> 16)) * dh;
    }
    for (int b = r0; b < r1; b += 64) {
        int cnt = min(64, r1 - b);
        int sv = n;          // pad: valid address, zero coefficient
        float cv = 0.f;
        if (lane < cnt) {
            sv = srcs[b + lane];
            cv = dis[sv] * dn;
        }
        int pairs = (cnt + 1) >> 1;
        int pR = (pairs + 7) & ~7;
        for (int j = 0; j < pR; j += 8) {
            uint2 u[8];
#pragma unroll
            for (int t = 0; t < 8; t++) {
                int e0 = 2 * (j + t);
                int s0 = __builtin_amdgcn_readlane(sv, e0);
                int s1 = __builtin_amdgcn_readlane(sv, e0 + 1);
                int ss = hi ? s1 : s0;
                u[t] = *(const uint2*)&hW[(long)ss * 128 + l32 * 4];
            }
#pragma unroll
            for (int t = 0; t < 8; t++) {
                int e0 = 2 * (j + t);
                float c0 = rdlanef(cv, e0);
                float c1 = rdlanef(cv, e0 + 1);
                float c = hi ? c1 : c0;
                a0 += bf2f((unsigned short)(u[t].x & 0xffff)) * c;
                a1 += bf2f((unsigned short)(u[t].x >> 16)) * c;
                a2 += bf2f((unsigned short)(u[t].y & 0xffff)) * c;
                a3 += bf2f((unsigned short)(u[t].y >> 16)) * c;
            }
        }
    }
    // merge even/odd halves (lane l and l+32 own the same 4 columns)
    a0 += __shfl_xor(a0, 32);
    a1 += __shfl_xor(a1, 32);
    a2 += __shfl_xor(a2, 32);
    a3 += __shfl_xor(a3, 32);
    float4 bb = *(const float4*)&bias[l32 * 4];
    a0 += bb.x; a1 += bb.y; a2 += bb.z; a3 += bb.w;
    float s = a0 + a1 + a2 + a3;
    float s2 = a0 * a0 + a1 * a1 + a2 * a2 + a3 * a3;
#pragma unroll
    for (int off = 1; off < 32; off <<= 1) { s += __shfl_xor(s, off); s2 += __shfl_xor(s2, off); }
    float mean = s * (1.f / 128.f);
    float var = s2 * (1.f / 128.f) - mean * mean;
    float is = rsqrtf(var + EPS);
    float4 gg = *(const float4*)&gamma[l32 * 4];
    float4 be4 = *(const float4*)&beta[l32 * 4];
    float y0 = fmaxf((a0 - mean) * is * gg.x + be4.x, 0.f);
    float y1 = fmaxf((a1 - mean) * is * gg.y + be4.y, 0.f);
    float y2 = fmaxf((a2 - mean) * is * gg.z + be4.z, 0.f);
    float y3 = fmaxf((a3 - mean) * is * gg.w + be4.w, 0.f);
    if (with_resid) {
        uint2 ru = *(const uint2*)&h16[(long)n * 128 + l32 * 4];
        y0 += bf2f((unsigned short)(ru.x & 0xffff));
        y1 += bf2f((unsigned short)(ru.x >> 16));
        y2 += bf2f((unsigned short)(ru.y & 0xffff));
        y3 += bf2f((unsigned short)(ru.y >> 16));
    }
    if (hi == 0) {
        uint2 outu;
        outu.x = (unsigned)bfbits(y0) | ((unsigned)bfbits(y1) << 16);
        outu.y = (unsigned)bfbits(y2) | ((unsigned)bfbits(y3) << 16);
        *(uint2*)&h16[(long)n * 128 + l32 * 4] = outu;
    }
}

// ---------------- attention: MFMA (swapped QK^T), bf16 output ----------------
__global__ __launch_bounds__(256) void attention(const unsigned short* __restrict__ q16,
                                                 const unsigned short* __restrict__ k16,
                                                 const unsigned short* __restrict__ v16,
                                                 unsigned short* __restrict__ o16) {
    int g = blockIdx.x, hh = blockIdx.y;
    int tid = threadIdx.x;
    long gbase = ((long)g * NPG) * 128 + hh * 16;
    __shared__ unsigned short Ksh[256][24];
    __shared__ unsigned short Qsh[256][24];
    __shared__ unsigned short Vt[16][264];
    {
        const unsigned short* kp = k16 + gbase + (long)tid * 128;
        uint4 a = *(const uint4*)kp, b = *(const uint4*)(kp + 8);
        *(uint4*)&Ksh[tid][0] = a; *(uint4*)&Ksh[tid][8] = b;
        const unsigned short* qp = q16 + gbase + (long)tid * 128;
        uint4 c = *(const uint4*)qp, d = *(const uint4*)(qp + 8);
        *(uint4*)&Qsh[tid][0] = c; *(uint4*)&Qsh[tid][8] = d;
        const unsigned short* vp = v16 + gbase + (long)tid * 128;
#pragma unroll
        for (int dd = 0; dd < 16; dd++) Vt[dd][tid] = vp[dd];
    }
    __syncthreads();
    int wv = tid >> 6, lane = tid & 63;
    int qg = lane >> 4, ql = lane & 15;
    bf16x4 vfrag[16];
#pragma unroll
    for (int kt = 0; kt < 16; kt++)
        vfrag[kt] = *(const bf16x4*)&Vt[ql][kt * 16 + qg * 4];
    const float C = 0.36067376022224085f;   // 0.25 * log2(e)
    for (int qi = 0; qi < 4; qi++) {
        int qt = wv * 4 + qi;
        bf16x4 qfrag = *(const bf16x4*)&Qsh[qt * 16 + ql][qg * 4];
        float lsum = 0.f;
        bf16x4 pb[16];
        f32x4 z4 = {0.f, 0.f, 0.f, 0.f};
#pragma unroll
        for (int kt = 0; kt < 16; kt++) {
            bf16x4 kfrag = *(const bf16x4*)&Ksh[kt * 16 + ql][qg * 4];
            f32x4 s4 = __builtin_amdgcn_mfma_f32_16x16x16bf16_1k(kfrag, qfrag, z4, 0, 0, 0);
            bf16x4 pbk;
#pragma unroll
            for (int r = 0; r < 4; r++) {
                float pv = exp2f(s4[r] * C);
                lsum += pv;
                pbk[r] = (short)bfbits(pv);
            }
            pb[kt] = pbk;
        }
        f32x4 oacc = {0.f, 0.f, 0.f, 0.f};
#pragma unroll
        for (int kt = 0; kt < 16; kt++)
            oacc = __builtin_amdgcn_mfma_f32_16x16x16bf16_1k(vfrag[kt], pb[kt], oacc, 0, 0, 0);
        lsum += __shfl_xor(lsum, 16);
        lsum += __shfl_xor(lsum, 32);
        float inv = 1.f / lsum;
        unsigned short* op = o16 + gbase + (long)(qt * 16 + ql) * 128 + 4 * qg;
        ushort4 st;
        st.x = bfbits(oacc[0] * inv);
        st.y = bfbits(oacc[1] * inv);
        st.z = bfbits(oacc[2] * inv);
        st.w = bfbits(oacc[3] * inv);
        *(ushort4*)op = st;
    }
}

// ---------------- fused pooling + classifier ----------------
__global__ __launch_bounds__(256) void pool_classifier(const unsigned short* __restrict__ hg,
                                                       const float* __restrict__ W1, const float* __restrict__ b1,
                                                       const float* __restrict__ g1, const float* __restrict__ be1,
                                                       const float* __restrict__ W2, const float* __restrict__ b2,
                                                       const float* __restrict__ W3, const float* __restrict__ b3,
                                                       float* __restrict__ out) {
    int g = blockIdx.x;
    int tid = threadIdx.x;
    int lane = tid & 63, grp = tid >> 6;
    __shared__ float ssum[4][128];
    __shared__ float smax[4][128];
    __shared__ float pl[384];
    __shared__ float zpart[2][128];
    __shared__ float z1s[128];
    __shared__ float z2s[64];
    __shared__ float red8[8];
    // pool phase
    float s0 = 0.f, s1 = 0.f, m0 = -1e30f, m1 = -1e30f;
    for (int i = grp * 64; i < grp * 64 + 64; i++) {
        unsigned u = *(const unsigned*)&hg[((long)g * NPG + i) * 128 + lane * 2];
        float v0 = bf2f((unsigned short)(u & 0xffff));
        float v1 = bf2f((unsigned short)(u >> 16));
        s0 += v0; s1 += v1;
        m0 = fmaxf(m0, v0); m1 = fmaxf(m1, v1);
    }
    ssum[grp][lane * 2] = s0; ssum[grp][lane * 2 + 1] = s1;
    smax[grp][lane * 2] = m0; smax[grp][lane * 2 + 1] = m1;
    __syncthreads();
    if (tid < 128) {
        float ts = ssum[0][tid] + ssum[1][tid] + ssum[2][tid] + ssum[3][tid];
        float tm = fmaxf(fmaxf(smax[0][tid], smax[1][tid]), fmaxf(smax[2][tid], smax[3][tid]));
        pl[tid] = ts * (1.f / 256.f);
        pl[128 + tid] = tm;
        pl[256 + tid] = ts;
    }
    __syncthreads();
    // classifier: z1 = relu(LN(pl @ W1 + b1))
    {
        int j = tid & 127, half = tid >> 7;
        float part = 0.f;
        for (int kk = half * 192; kk < half * 192 + 192; kk++)
            part += pl[kk] * W1[kk * 128 + j];
        zpart[half][j] = part;
    }
    __syncthreads();
    float acc = 0.f;
    if (tid < 128) acc = b1[tid] + zpart[0][tid] + zpart[1][tid];
    float m, is;
    ln_stats256(tid < 128 ? acc : 0.f, m, is, red8);
    if (tid < 128) z1s[tid] = fmaxf((acc - m) * is * g1[tid] + be1[tid], 0.f);
    __syncthreads();
    if (tid < 64) {
        float a2 = b2[tid];
        for (int kk = 0; kk < 128; kk++) a2 += z1s[kk] * W2[kk * 64 + tid];
        z2s[tid] = fmaxf(a2, 0.f);
    }
    __syncthreads();
    if (tid < 64) {
        float vv = z2s[tid];
        float p0 = vv * W3[tid * 2];
        float p1 = vv * W3[tid * 2 + 1];
#pragma unroll
        for (int off = 32; off; off >>= 1) { p0 += __shfl_xor(p0, off); p1 += __shfl_xor(p1, off); }
        if (tid == 0) {
            out[g * 2] = p0 + b3[0];
            out[g * 2 + 1] = p1 + b3[1];
        }
    }
}

// ---------------- launch ----------------
extern "C" void kernel_launch(void* const* d_in, const int* in_sizes, int n_in,
                              void* d_out, int out_size, void* d_ws, size_t ws_size,
                              hipStream_t stream) {
    const float* x = (const float*)d_in[0];
    const int* ei = (const int*)d_in[1];
    const float* W_in = (const float*)d_in[3];
    const float* b_in = (const float*)d_in[4];
    const float* g_in = (const float*)d_in[5];
    const float* be_in = (const float*)d_in[6];
    const float* Wc = (const float*)d_in[7];
    const float* bc = (const float*)d_in[8];
    const float* gn = (const float*)d_in[9];
    const float* bn = (const float*)d_in[10];
    const float* Wq = (const float*)d_in[11];
    const float* bq = (const float*)d_in[12];
    const float* Wk = (const float*)d_in[13];
    const float* bk = (const float*)d_in[14];
    const float* Wv = (const float*)d_in[15];
    const float* bv = (const float*)d_in[16];
    const float* Wo = (const float*)d_in[17];
    const float* bo = (const float*)d_in[18];
    const float* ga = (const float*)d_in[19];
    const float* ba = (const float*)d_in[20];
    const float* W1 = (const float*)d_in[21];
    const float* b1 = (const float*)d_in[22];
    const float* g1 = (const float*)d_in[23];
    const float* be1 = (const float*)d_in[24];
    const float* W2 = (const float*)d_in[25];
    const float* b2 = (const float*)d_in[26];
    const float* W3 = (const float*)d_in[27];
    const float* b3 = (const float*)d_in[28];
    float* out = (float*)d_out;

    const long NF = (long)N_NODES * 128;
    unsigned char* wsb = (unsigned char*)d_ws;
    const size_t MB = 1 << 20;
    unsigned short* h16 = (unsigned short*)(wsb);             // 8MB
    unsigned short* hw16 = (unsigned short*)(wsb + 8 * MB);   // 8MB
    unsigned short* qkv16 = (unsigned short*)(wsb + 16 * MB); // 24MB
    unsigned short* o16 = (unsigned short*)(wsb + 40 * MB);   // 8MB
    unsigned short* hg16 = (unsigned short*)(wsb + 48 * MB);  // 8MB
    unsigned short* Wpk = (unsigned short*)(wsb + 56 * MB);   // 224KB
    int* packed = (int*)(wsb + 57 * MB);                      // 4MB
    int* srcs = (int*)(wsb + 61 * MB);                        // 4MB
    int* row_ptr = (int*)(wsb + 65 * MB);                     // 128KB+4
    float* dis = (float*)(wsb + 66 * MB);                     // 128KB
    float* bT = (float*)(wsb + 67 * MB);                      // 1.5KB
    int* bucket_cnt = (int*)(wsb + 68 * MB);                  // 256
    int* bucket_base = bucket_cnt + 256;                      // 257
    int* bucket_fill = bucket_base + 257;                     // 256

    const int* e_src = ei;
    const int* e_dst = ei + E_EDGES;

    hipMemsetAsync(bucket_cnt, 0, 256 * sizeof(int), stream);
    prep_weights<<<dim3(64, 7), 256, 0, stream>>>(Wc, Wq, Wk, Wv, Wo, bq, bk, bv, Wpk, bT);
    bucket_count<<<E_EDGES / CHUNK, 256, 0, stream>>>(e_dst, bucket_cnt);
    scan_buckets<<<1, 256, 0, stream>>>(bucket_cnt, bucket_base, bucket_fill);
    bucket_scatter<<<E_EDGES / CHUNK, 256, 0, stream>>>(e_src, e_dst, bucket_fill, packed);
    csr_build<<<256, 256, 0, stream>>>(bucket_base, packed, srcs, row_ptr, dis);

    input_proj<<<N_NODES / 4, 256, 0, stream>>>(x, W_in, b_in, g_in, be_in, h16);

    for (int i = 0; i < 3; i++) {
        gemm_mfma<0><<<N_NODES / 64, 256, 0, stream>>>(h16, Wpk + i * 16384, nullptr, nullptr,
                                                       nullptr, nullptr, hw16);
        gcn_agg<<<N_NODES / 4, 256, 0, stream>>>(hw16, row_ptr, srcs, dis, bc + i * 128,
                                                 gn + i * 128, bn + i * 128, h16, i > 0);
    }

    gemm_qkv<<<dim3(N_NODES / 64, 3), 256, 0, stream>>>(h16, Wpk, bT, qkv16);

    attention<<<dim3(G_GRAPHS, NH), 256, 0, stream>>>(qkv16, qkv16 + NF, qkv16 + 2 * NF, o16);

    gemm_mfma<2><<<N_NODES / 64, 256, 0, stream>>>(o16, Wpk + 6 * 16384, bo, h16, ga, ba, hg16);

    pool_classifier<<<G_GRAPHS, 256, 0, stream>>>(hg16, W1, b1, g1, be1, W2, b2, W3, b3, out);
}

// Round 8
// 381.331 us; speedup vs baseline: 1.0045x; 1.0045x over previous
//
#include <hip/hip_runtime.h>
#include <hip/hip_bf16.h>

#define N_NODES 32768
#define E_EDGES 1048576
#define HID 128
#define G_GRAPHS 128
#define NPG 256
#define NH 8
#define DH 16
#define EPS 1e-5f
#define CHUNK 4096
#define BCAP 8192

typedef __attribute__((ext_vector_type(4))) float f32x4;
typedef __attribute__((ext_vector_type(4))) short bf16x4;

static __device__ __forceinline__ unsigned short bfbits(float f) {
    return __builtin_bit_cast(unsigned short, __float2bfloat16(f));
}
static __device__ __forceinline__ float bf2f(unsigned short u) {
    return __builtin_bit_cast(float, (unsigned)u << 16);
}
static __device__ __forceinline__ float rdlanef(float v, int l) {
    return __builtin_bit_cast(float, __builtin_amdgcn_readlane(__builtin_bit_cast(int, v), l));
}

// ---------------- helpers ----------------
// 256-thread block, 128 live values (threads >=128 pass v=0)
__device__ __forceinline__ void ln_stats256(float v, float& mean, float& istd, float* red8) {
    float s = v, s2 = v * v;
#pragma unroll
    for (int off = 32; off; off >>= 1) { s += __shfl_xor(s, off); s2 += __shfl_xor(s2, off); }
    int w = threadIdx.x >> 6;
    if ((threadIdx.x & 63) == 0) { red8[w * 2] = s; red8[w * 2 + 1] = s2; }
    __syncthreads();
    float ts = red8[0] + red8[2] + red8[4] + red8[6];
    float ts2 = red8[1] + red8[3] + red8[5] + red8[7];
    mean = ts * (1.f / 128.f);
    float var = ts2 * (1.f / 128.f) - mean * mean;
    istd = rsqrtf(var + EPS);
    __syncthreads();
}

// ---------------- CSR build: bucketed counting sort ----------------
__global__ __launch_bounds__(256) void bucket_count(const int* __restrict__ dst,
                                                    int* __restrict__ bucket_cnt) {
    __shared__ int bcnt[256];
    int tid = threadIdx.x;
    bcnt[tid] = 0;
    __syncthreads();
    int base = blockIdx.x * CHUNK;
#pragma unroll
    for (int j = 0; j < 16; j++) {
        int d = dst[base + j * 256 + tid];
        atomicAdd(&bcnt[d >> 7], 1);
    }
    __syncthreads();
    atomicAdd(&bucket_cnt[tid], bcnt[tid]);
}

__global__ __launch_bounds__(256) void scan_buckets(const int* __restrict__ bucket_cnt,
                                                    int* __restrict__ bucket_base,
                                                    int* __restrict__ bucket_fill) {
    __shared__ int sc[256];
    int t = threadIdx.x;
    int c = bucket_cnt[t];
    sc[t] = c;
    __syncthreads();
    for (int off = 1; off < 256; off <<= 1) {
        int v = (t >= off) ? sc[t - off] : 0;
        __syncthreads();
        sc[t] += v;
        __syncthreads();
    }
    int ex = sc[t] - c;
    bucket_base[t] = ex;
    bucket_fill[t] = ex;
    if (t == 255) bucket_base[256] = sc[255];
}

__global__ __launch_bounds__(256) void bucket_scatter(const int* __restrict__ src,
                                                      const int* __restrict__ dst,
                                                      int* __restrict__ bucket_fill,
                                                      int* __restrict__ packed) {
    __shared__ int bcnt[256];
    __shared__ int lsc[256];
    __shared__ int delta[256];
    __shared__ int sorted[CHUNK];
    int tid = threadIdx.x;
    int base = blockIdx.x * CHUNK;
    int pk[16], bk[16], rk[16];
    bcnt[tid] = 0;
    __syncthreads();
#pragma unroll
    for (int j = 0; j < 16; j++) {
        int e = base + j * 256 + tid;
        int d = dst[e], s = src[e];
        pk[j] = (d << 15) | s;
        bk[j] = d >> 7;
    }
#pragma unroll
    for (int j = 0; j < 16; j++) rk[j] = atomicAdd(&bcnt[bk[j]], 1);
    __syncthreads();
    int cnt_t = bcnt[tid];
    lsc[tid] = cnt_t;
    __syncthreads();
    for (int off = 1; off < 256; off <<= 1) {
        int v = (tid >= off) ? lsc[tid - off] : 0;
        __syncthreads();
        lsc[tid] += v;
        __syncthreads();
    }
    int ls_t = lsc[tid] - cnt_t;
    __syncthreads();
    lsc[tid] = ls_t;
    int g = 0;
    if (cnt_t > 0) g = atomicAdd(&bucket_fill[tid], cnt_t);
    delta[tid] = g - ls_t;
    __syncthreads();
#pragma unroll
    for (int j = 0; j < 16; j++) sorted[lsc[bk[j]] + rk[j]] = pk[j];
    __syncthreads();
    for (int i = tid; i < CHUNK; i += 256) {
        int u = sorted[i];
        int b2 = u >> 22;
        packed[delta[b2] + i] = u;
    }
}

__global__ __launch_bounds__(256) void csr_build(const int* __restrict__ bucket_base,
                                                 const int* __restrict__ packed,
                                                 int* __restrict__ srcs,
                                                 int* __restrict__ row_ptr,
                                                 float* __restrict__ dis) {
    __shared__ int ncnt[128];
    __shared__ int sc[128];
    __shared__ int fill[128];
    __shared__ int outl[BCAP];
    int b = blockIdx.x, tid = threadIdx.x;
    int c0 = bucket_base[b], c1 = bucket_base[b + 1];
    int cnt = c1 - c0;
    if (tid < 128) ncnt[tid] = 0;
    __syncthreads();
    for (int i = tid; i < cnt; i += 256) {
        int u = packed[c0 + i];
        atomicAdd(&ncnt[(u >> 15) & 127], 1);
    }
    __syncthreads();
    int c = (tid < 128) ? ncnt[tid] : 0;
    if (tid < 128) sc[tid] = c;
    __syncthreads();
    for (int off = 1; off < 128; off <<= 1) {
        int v = (tid < 128 && tid >= off) ? sc[tid - off] : 0;
        __syncthreads();
        if (tid < 128) sc[tid] += v;
        __syncthreads();
    }
    if (tid < 128) {
        int ex = sc[tid] - c;
        fill[tid] = ex;
        int node = b * 128 + tid;
        row_ptr[node] = c0 + ex;
        dis[node] = rsqrtf((float)(c + 1));
    }
    if (b == 255 && tid == 0) row_ptr[N_NODES] = c1;
    __syncthreads();
    if (cnt <= BCAP) {
        for (int i = tid; i < cnt; i += 256) {
            int u = packed[c0 + i];
            int p = atomicAdd(&fill[(u >> 15) & 127], 1);
            outl[p] = u & 32767;
        }
        __syncthreads();
        for (int i = tid; i < cnt; i += 256) srcs[c0 + i] = outl[i];
    } else {
        for (int i = tid; i < cnt; i += 256) {
            int u = packed[c0 + i];
            int p = atomicAdd(&fill[(u >> 15) & 127], 1);
            srcs[c0 + p] = u & 32767;
        }
    }
}

// ---------------- weight prep ----------------
__global__ __launch_bounds__(256) void prep_weights(const float* __restrict__ Wc,
                                                    const float* __restrict__ Wq,
                                                    const float* __restrict__ Wk,
                                                    const float* __restrict__ Wv,
                                                    const float* __restrict__ Wo,
                                                    const float* __restrict__ bq,
                                                    const float* __restrict__ bk,
                                                    const float* __restrict__ bv,
                                                    unsigned short* __restrict__ Wpk,
                                                    float* __restrict__ bT) {
    int m = blockIdx.y;
    int idx = blockIdx.x * 256 + threadIdx.x;   // 0..16383
    int j = idx & 3, ln = (idx >> 2) & 63, kt = (idx >> 8) & 7, jt = (idx >> 11) & 7;
    int k = kt * 16 + (ln >> 4) * 4 + j;
    int col = jt * 16 + (ln & 15);
    float val;
    if (m < 3) val = Wc[m * 16384 + k * 128 + col];
    else {
        const float* W = (m == 3) ? Wq : (m == 4) ? Wk : (m == 5) ? Wv : Wo;
        val = W[col * 128 + k];
    }
    Wpk[m * 16384 + idx] = bfbits(val);
    if (m >= 3 && m < 6 && idx < 128) {
        const float* bs = (m == 3) ? bq : (m == 4) ? bk : bv;
        bT[(m - 3) * 128 + idx] = bs[idx];
    }
}

// ---------------- input projection: wave-per-node ----------------
__global__ __launch_bounds__(256) void input_proj(const float* __restrict__ x,
                                                  const float* __restrict__ W,
                                                  const float* __restrict__ b,
                                                  const float* __restrict__ g,
                                                  const float* __restrict__ be,
                                                  unsigned short* __restrict__ h16) {
    int wv = threadIdx.x >> 6, lane = threadIdx.x & 63;
    int n = blockIdx.x * 4 + wv;
    float xv = (lane < 15) ? x[n * 15 + lane] : 0.f;
    int c = lane * 2;
    float2 bb = *(const float2*)&b[c];
    float a0 = bb.x, a1 = bb.y;
#pragma unroll
    for (int k = 0; k < 15; k++) {
        float xk = rdlanef(xv, k);
        float2 w2 = *(const float2*)&W[k * 128 + c];
        a0 += xk * w2.x;
        a1 += xk * w2.y;
    }
    float s = a0 + a1, s2 = a0 * a0 + a1 * a1;
#pragma unroll
    for (int off = 1; off < 64; off <<= 1) { s += __shfl_xor(s, off); s2 += __shfl_xor(s2, off); }
    float mean = s * (1.f / 128.f);
    float var = s2 * (1.f / 128.f) - mean * mean;
    float is = rsqrtf(var + EPS);
    float2 gg = *(const float2*)&g[c];
    float2 be2 = *(const float2*)&be[c];
    float y0 = fmaxf((a0 - mean) * is * gg.x + be2.x, 0.f);
    float y1 = fmaxf((a1 - mean) * is * gg.y + be2.y, 0.f);
    unsigned outu = (unsigned)bfbits(y0) | ((unsigned)bfbits(y1) << 16);
    *(unsigned*)&h16[(long)n * 128 + c] = outu;
}

// ---------------- MFMA GEMM ----------------
template <int MODE>
__device__ __forceinline__ void gemm_mfma_body(const unsigned short* __restrict__ in16,
                                               const unsigned short* __restrict__ Wpk,
                                               const float* __restrict__ bias,
                                               const unsigned short* __restrict__ resid16,
                                               const float* __restrict__ gamma,
                                               const float* __restrict__ beta,
                                               unsigned short* __restrict__ out16) {
    __shared__ unsigned short Ws[16384];
    __shared__ unsigned short Hs[64][136];
    int tid = threadIdx.x;
    long base = (long)blockIdx.x * 64;
    {
        const uint4* s4 = (const uint4*)Wpk;
        uint4* d4 = (uint4*)Ws;
        for (int i = tid; i < 2048; i += 256) d4[i] = s4[i];
        const unsigned short* hsrc = in16 + base * 128;
        for (int i = tid; i < 1024; i += 256) {
            int r = i >> 4, c8 = i & 15;
            *(uint4*)&Hs[r][c8 * 8] = *(const uint4*)&hsrc[r * 128 + c8 * 8];
        }
    }
    __syncthreads();
    int wv = tid >> 6, lane = tid & 63;
    int ql = lane & 15, qg = lane >> 4;
    f32x4 acc[8];
#pragma unroll
    for (int jt = 0; jt < 8; jt++) acc[jt] = (f32x4){0.f, 0.f, 0.f, 0.f};
#pragma unroll
    for (int kt = 0; kt < 8; kt++) {
        bf16x4 af = *(const bf16x4*)&Hs[wv * 16 + ql][kt * 16 + qg * 4];
#pragma unroll
        for (int jt = 0; jt < 8; jt++) {
            bf16x4 bf = *(const bf16x4*)&Ws[((jt * 8 + kt) * 64 + lane) * 4];
            acc[jt] = __builtin_amdgcn_mfma_f32_16x16x16bf16_1k(af, bf, acc[jt], 0, 0, 0);
        }
    }
    if (MODE >= 1) {
#pragma unroll
        for (int jt = 0; jt < 8; jt++) {
            float bv = bias[jt * 16 + ql];
#pragma unroll
            for (int r = 0; r < 4; r++) acc[jt][r] += bv;
        }
    }
    if (MODE == 2) {
#pragma unroll
        for (int jt = 0; jt < 8; jt++)
#pragma unroll
            for (int r = 0; r < 4; r++)
                acc[jt][r] += bf2f(resid16[(base + wv * 16 + qg * 4 + r) * 128 + jt * 16 + ql]);
        float s[4], s2[4], mean[4], istd[4];
#pragma unroll
        for (int r = 0; r < 4; r++) { s[r] = 0.f; s2[r] = 0.f; }
#pragma unroll
        for (int jt = 0; jt < 8; jt++)
#pragma unroll
            for (int r = 0; r < 4; r++) { float v = acc[jt][r]; s[r] += v; s2[r] += v * v; }
#pragma unroll
        for (int off = 1; off < 16; off <<= 1)
#pragma unroll
            for (int r = 0; r < 4; r++) {
                s[r] += __shfl_xor(s[r], off);
                s2[r] += __shfl_xor(s2[r], off);
            }
#pragma unroll
        for (int r = 0; r < 4; r++) {
            mean[r] = s[r] * (1.f / 128.f);
            float var = s2[r] * (1.f / 128.f) - mean[r] * mean[r];
            istd[r] = rsqrtf(var + EPS);
        }
#pragma unroll
        for (int jt = 0; jt < 8; jt++) {
            float gv = gamma[jt * 16 + ql], bev = beta[jt * 16 + ql];
#pragma unroll
            for (int r = 0; r < 4; r++)
                acc[jt][r] = (acc[jt][r] - mean[r]) * istd[r] * gv + bev;
        }
    }
#pragma unroll
    for (int jt = 0; jt < 8; jt++)
#pragma unroll
        for (int r = 0; r < 4; r++)
            Hs[wv * 16 + qg * 4 + r][jt * 16 + ql] = bfbits(acc[jt][r]);
#pragma unroll
    for (int p = 0; p < 4; p++) {
        int rl = p * 4 + qg;
        uint4 v = *(const uint4*)&Hs[wv * 16 + rl][ql * 8];
        *(uint4*)&out16[(base + wv * 16 + rl) * 128 + ql * 8] = v;
    }
}

template <int MODE>
__global__ __launch_bounds__(256) void gemm_mfma(const unsigned short* __restrict__ in16,
                                                 const unsigned short* __restrict__ Wpk,
                                                 const float* __restrict__ bias,
                                                 const unsigned short* __restrict__ resid16,
                                                 const float* __restrict__ gamma,
                                                 const float* __restrict__ beta,
                                                 unsigned short* __restrict__ out16) {
    gemm_mfma_body<MODE>(in16, Wpk, bias, resid16, gamma, beta, out16);
}

__global__ __launch_bounds__(256) void gemm_qkv(const unsigned short* __restrict__ in16,
                                                const unsigned short* __restrict__ Wpk,
                                                const float* __restrict__ bT,
                                                unsigned short* __restrict__ outb) {
    int y = blockIdx.y;
    gemm_mfma_body<1>(in16, Wpk + (3 + y) * 16384, bT + y * 128, nullptr, nullptr, nullptr,
                      outb + (long)y * N_NODES * 128);
}

// ---------------- GCN aggregation v6: uniform-row dword gather, 32-deep MLP --------
// v5 lesson: keep the row address WAVE-UNIFORM (readlane -> SGPR base + lane voffset);
// lane-divergent row select forces 64-bit VGPR addressing and regresses.
__global__ __launch_bounds__(256) void gcn_agg(const unsigned short* __restrict__ hW,
                                               const int* __restrict__ row_ptr,
                                               const int* __restrict__ srcs,
                                               const float* __restrict__ dis,
                                               const float* __restrict__ bias,
                                               const float* __restrict__ gamma,
                                               const float* __restrict__ beta,
                                               unsigned short* __restrict__ h16, int with_resid) {
    int wv = threadIdx.x >> 6, lane = threadIdx.x & 63;
    int n = blockIdx.x * 4 + wv;
    int r0 = row_ptr[n], r1 = row_ptr[n + 1];
    float dn = dis[n];
    unsigned su = *(const unsigned*)&hW[(long)n * 128 + lane * 2];
    float dnn = dn * dn;
    float a0 = bf2f((unsigned short)(su & 0xffff)) * dnn;
    float a1 = bf2f((unsigned short)(su >> 16)) * dnn;
    for (int b = r0; b < r1; b += 64) {
        int cnt = min(64, r1 - b);
        int sv = n;          // pad: valid (hot) address, zero coefficient
        float cv = 0.f;
        if (lane < cnt) {
            sv = srcs[b + lane];
            cv = dis[sv] * dn;
        }
        int cntR = (cnt + 31) & ~31;
        for (int j = 0; j < cntR; j += 32) {
            unsigned u[32];
#pragma unroll
            for (int t = 0; t < 32; t++) {
                int s = __builtin_amdgcn_readlane(sv, j + t);
                u[t] = *(const unsigned*)&hW[(long)s * 128 + lane * 2];
            }
#pragma unroll
            for (int t = 0; t < 32; t++) {
                float c = rdlanef(cv, j + t);
                a0 += bf2f((unsigned short)(u[t] & 0xffff)) * c;
                a1 += bf2f((unsigned short)(u[t] >> 16)) * c;
            }
        }
    }
    float2 bb = *(const float2*)&bias[lane * 2];
    a0 += bb.x;
    a1 += bb.y;
    float s = a0 + a1, s2 = a0 * a0 + a1 * a1;
#pragma unroll
    for (int off = 1; off < 64; off <<= 1) { s += __shfl_xor(s, off); s2 += __shfl_xor(s2, off); }
    float mean = s * (1.f / 128.f);
    float var = s2 * (1.f / 128.f) - mean * mean;
    float is = rsqrtf(var + EPS);
    float2 gg = *(const float2*)&gamma[lane * 2];
    float2 be2 = *(const float2*)&beta[lane * 2];
    float y0 = fmaxf((a0 - mean) * is * gg.x + be2.x, 0.f);
    float y1 = fmaxf((a1 - mean) * is * gg.y + be2.y, 0.f);
    if (with_resid) {
        unsigned ru = *(const unsigned*)&h16[(long)n * 128 + lane * 2];
        y0 += bf2f((unsigned short)(ru & 0xffff));
        y1 += bf2f((unsigned short)(ru >> 16));
    }
    unsigned outu = (unsigned)bfbits(y0) | ((unsigned)bfbits(y1) << 16);
    *(unsigned*)&h16[(long)n * 128 + lane * 2] = outu;
}

// ---------------- attention: MFMA (swapped QK^T), bf16 output ----------------
__global__ __launch_bounds__(256) void attention(const unsigned short* __restrict__ q16,
                                                 const unsigned short* __restrict__ k16,
                                                 const unsigned short* __restrict__ v16,
                                                 unsigned short* __restrict__ o16) {
    int g = blockIdx.x, hh = blockIdx.y;
    int tid = threadIdx.x;
    long gbase = ((long)g * NPG) * 128 + hh * 16;
    __shared__ unsigned short Ksh[256][24];
    __shared__ unsigned short Qsh[256][24];
    __shared__ unsigned short Vt[16][264];
    {
        const unsigned short* kp = k16 + gbase + (long)tid * 128;
        uint4 a = *(const uint4*)kp, b = *(const uint4*)(kp + 8);
        *(uint4*)&Ksh[tid][0] = a; *(uint4*)&Ksh[tid][8] = b;
        const unsigned short* qp = q16 + gbase + (long)tid * 128;
        uint4 c = *(const uint4*)qp, d = *(const uint4*)(qp + 8);
        *(uint4*)&Qsh[tid][0] = c; *(uint4*)&Qsh[tid][8] = d;
        const unsigned short* vp = v16 + gbase + (long)tid * 128;
#pragma unroll
        for (int dd = 0; dd < 16; dd++) Vt[dd][tid] = vp[dd];
    }
    __syncthreads();
    int wv = tid >> 6, lane = tid & 63;
    int qg = lane >> 4, ql = lane & 15;
    bf16x4 vfrag[16];
#pragma unroll
    for (int kt = 0; kt < 16; kt++)
        vfrag[kt] = *(const bf16x4*)&Vt[ql][kt * 16 + qg * 4];
    const float C = 0.36067376022224085f;   // 0.25 * log2(e)
    for (int qi = 0; qi < 4; qi++) {
        int qt = wv * 4 + qi;
        bf16x4 qfrag = *(const bf16x4*)&Qsh[qt * 16 + ql][qg * 4];
        float lsum = 0.f;
        bf16x4 pb[16];
        f32x4 z4 = {0.f, 0.f, 0.f, 0.f};
#pragma unroll
        for (int kt = 0; kt < 16; kt++) {
            bf16x4 kfrag = *(const bf16x4*)&Ksh[kt * 16 + ql][qg * 4];
            f32x4 s4 = __builtin_amdgcn_mfma_f32_16x16x16bf16_1k(kfrag, qfrag, z4, 0, 0, 0);
            bf16x4 pbk;
#pragma unroll
            for (int r = 0; r < 4; r++) {
                float pv = exp2f(s4[r] * C);
                lsum += pv;
                pbk[r] = (short)bfbits(pv);
            }
            pb[kt] = pbk;
        }
        f32x4 oacc = {0.f, 0.f, 0.f, 0.f};
#pragma unroll
        for (int kt = 0; kt < 16; kt++)
            oacc = __builtin_amdgcn_mfma_f32_16x16x16bf16_1k(vfrag[kt], pb[kt], oacc, 0, 0, 0);
        lsum += __shfl_xor(lsum, 16);
        lsum += __shfl_xor(lsum, 32);
        float inv = 1.f / lsum;
        unsigned short* op = o16 + gbase + (long)(qt * 16 + ql) * 128 + 4 * qg;
        ushort4 st;
        st.x = bfbits(oacc[0] * inv);
        st.y = bfbits(oacc[1] * inv);
        st.z = bfbits(oacc[2] * inv);
        st.w = bfbits(oacc[3] * inv);
        *(ushort4*)op = st;
    }
}

// ---------------- fused pooling + classifier ----------------
__global__ __launch_bounds__(256) void pool_classifier(const unsigned short* __restrict__ hg,
                                                       const float* __restrict__ W1, const float* __restrict__ b1,
                                                       const float* __restrict__ g1, const float* __restrict__ be1,
                                                       const float* __restrict__ W2, const float* __restrict__ b2,
                                                       const float* __restrict__ W3, const float* __restrict__ b3,
                                                       float* __restrict__ out) {
    int g = blockIdx.x;
    int tid = threadIdx.x;
    int lane = tid & 63, grp = tid >> 6;
    __shared__ float ssum[4][128];
    __shared__ float smax[4][128];
    __shared__ float pl[384];
    __shared__ float zpart[2][128];
    __shared__ float z1s[128];
    __shared__ float z2s[64];
    __shared__ float red8[8];
    float s0 = 0.f, s1 = 0.f, m0 = -1e30f, m1 = -1e30f;
    for (int i = grp * 64; i < grp * 64 + 64; i++) {
        unsigned u = *(const unsigned*)&hg[((long)g * NPG + i) * 128 + lane * 2];
        float v0 = bf2f((unsigned short)(u & 0xffff));
        float v1 = bf2f((unsigned short)(u >> 16));
        s0 += v0; s1 += v1;
        m0 = fmaxf(m0, v0); m1 = fmaxf(m1, v1);
    }
    ssum[grp][lane * 2] = s0; ssum[grp][lane * 2 + 1] = s1;
    smax[grp][lane * 2] = m0; smax[grp][lane * 2 + 1] = m1;
    __syncthreads();
    if (tid < 128) {
        float ts = ssum[0][tid] + ssum[1][tid] + ssum[2][tid] + ssum[3][tid];
        float tm = fmaxf(fmaxf(smax[0][tid], smax[1][tid]), fmaxf(smax[2][tid], smax[3][tid]));
        pl[tid] = ts * (1.f / 256.f);
        pl[128 + tid] = tm;
        pl[256 + tid] = ts;
    }
    __syncthreads();
    {
        int j = tid & 127, half = tid >> 7;
        float part = 0.f;
        for (int kk = half * 192; kk < half * 192 + 192; kk++)
            part += pl[kk] * W1[kk * 128 + j];
        zpart[half][j] = part;
    }
    __syncthreads();
    float acc = 0.f;
    if (tid < 128) acc = b1[tid] + zpart[0][tid] + zpart[1][tid];
    float m, is;
    ln_stats256(tid < 128 ? acc : 0.f, m, is, red8);
    if (tid < 128) z1s[tid] = fmaxf((acc - m) * is * g1[tid] + be1[tid], 0.f);
    __syncthreads();
    if (tid < 64) {
        float a2 = b2[tid];
        for (int kk = 0; kk < 128; kk++) a2 += z1s[kk] * W2[kk * 64 + tid];
        z2s[tid] = fmaxf(a2, 0.f);
    }
    __syncthreads();
    if (tid < 64) {
        float vv = z2s[tid];
        float p0 = vv * W3[tid * 2];
        float p1 = vv * W3[tid * 2 + 1];
#pragma unroll
        for (int off = 32; off; off >>= 1) { p0 += __shfl_xor(p0, off); p1 += __shfl_xor(p1, off); }
        if (tid == 0) {
            out[g * 2] = p0 + b3[0];
            out[g * 2 + 1] = p1 + b3[1];
        }
    }
}

// ---------------- launch ----------------
extern "C" void kernel_launch(void* const* d_in, const int* in_sizes, int n_in,
                              void* d_out, int out_size, void* d_ws, size_t ws_size,
                              hipStream_t stream) {
    const float* x = (const float*)d_in[0];
    const int* ei = (const int*)d_in[1];
    const float* W_in = (const float*)d_in[3];
    const float* b_in = (const float*)d_in[4];
    const float* g_in = (const float*)d_in[5];
    const float* be_in = (const float*)d_in[6];
    const float* Wc = (const float*)d_in[7];
    const float* bc = (const float*)d_in[8];
    const float* gn = (const float*)d_in[9];
    const float* bn = (const float*)d_in[10];
    const float* Wq = (const float*)d_in[11];
    const float* bq = (const float*)d_in[12];
    const float* Wk = (const float*)d_in[13];
    const float* bk = (const float*)d_in[14];
    const float* Wv = (const float*)d_in[15];
    const float* bv = (const float*)d_in[16];
    const float* Wo = (const float*)d_in[17];
    const float* bo = (const float*)d_in[18];
    const float* ga = (const float*)d_in[19];
    const float* ba = (const float*)d_in[20];
    const float* W1 = (const float*)d_in[21];
    const float* b1 = (const float*)d_in[22];
    const float* g1 = (const float*)d_in[23];
    const float* be1 = (const float*)d_in[24];
    const float* W2 = (const float*)d_in[25];
    const float* b2 = (const float*)d_in[26];
    const float* W3 = (const float*)d_in[27];
    const float* b3 = (const float*)d_in[28];
    float* out = (float*)d_out;

    const long NF = (long)N_NODES * 128;
    unsigned char* wsb = (unsigned char*)d_ws;
    const size_t MB = 1 << 20;
    unsigned short* h16 = (unsigned short*)(wsb);             // 8MB
    unsigned short* hw16 = (unsigned short*)(wsb + 8 * MB);   // 8MB
    unsigned short* qkv16 = (unsigned short*)(wsb + 16 * MB); // 24MB
    unsigned short* o16 = (unsigned short*)(wsb + 40 * MB);   // 8MB
    unsigned short* hg16 = (unsigned short*)(wsb + 48 * MB);  // 8MB
    unsigned short* Wpk = (unsigned short*)(wsb + 56 * MB);   // 224KB
    int* packed = (int*)(wsb + 57 * MB);                      // 4MB
    int* srcs = (int*)(wsb + 61 * MB);                        // 4MB
    int* row_ptr = (int*)(wsb + 65 * MB);                     // 128KB+4
    float* dis = (float*)(wsb + 66 * MB);                     // 128KB
    float* bT = (float*)(wsb + 67 * MB);                      // 1.5KB
    int* bucket_cnt = (int*)(wsb + 68 * MB);                  // 256
    int* bucket_base = bucket_cnt + 256;                      // 257
    int* bucket_fill = bucket_base + 257;                     // 256

    const int* e_src = ei;
    const int* e_dst = ei + E_EDGES;

    hipMemsetAsync(bucket_cnt, 0, 256 * sizeof(int), stream);
    prep_weights<<<dim3(64, 7), 256, 0, stream>>>(Wc, Wq, Wk, Wv, Wo, bq, bk, bv, Wpk, bT);
    bucket_count<<<E_EDGES / CHUNK, 256, 0, stream>>>(e_dst, bucket_cnt);
    scan_buckets<<<1, 256, 0, stream>>>(bucket_cnt, bucket_base, bucket_fill);
    bucket_scatter<<<E_EDGES / CHUNK, 256, 0, stream>>>(e_src, e_dst, bucket_fill, packed);
    csr_build<<<256, 256, 0, stream>>>(bucket_base, packed, srcs, row_ptr, dis);

    input_proj<<<N_NODES / 4, 256, 0, stream>>>(x, W_in, b_in, g_in, be_in, h16);

    for (int i = 0; i < 3; i++) {
        gemm_mfma<0><<<N_NODES / 64, 256, 0, stream>>>(h16, Wpk + i * 16384, nullptr, nullptr,
                                                       nullptr, nullptr, hw16);
        gcn_agg<<<N_NODES / 4, 256, 0, stream>>>(hw16, row_ptr, srcs, dis, bc + i * 128,
                                                 gn + i * 128, bn + i * 128, h16, i > 0);
    }

    gemm_qkv<<<dim3(N_NODES / 64, 3), 256, 0, stream>>>(h16, Wpk, bT, qkv16);

    attention<<<dim3(G_GRAPHS, NH), 256, 0, stream>>>(qkv16, qkv16 + NF, qkv16 + 2 * NF, o16);

    gemm_mfma<2><<<N_NODES / 64, 256, 0, stream>>>(o16, Wpk + 6 * 16384, bo, h16, ga, ba, hg16);

    pool_classifier<<<G_GRAPHS, 256, 0, stream>>>(hg16, W1, b1, g1, be1, W2, b2, W3, b3, out);
}

// Round 9
// 366.979 us; speedup vs baseline: 1.0438x; 1.0391x over previous
//
#include <hip/hip_runtime.h>
#include <hip/hip_bf16.h>

#define N_NODES 32768
#define E_EDGES 1048576
#define HID 128
#define G_GRAPHS 128
#define NPG 256
#define NH 8
#define DH 16
#define EPS 1e-5f
#define CHUNK 4096
#define BCAP 8192

typedef __attribute__((ext_vector_type(4))) float f32x4;
typedef __attribute__((ext_vector_type(4))) short bf16x4;

static __device__ __forceinline__ unsigned short bfbits(float f) {
    return __builtin_bit_cast(unsigned short, __float2bfloat16(f));
}
static __device__ __forceinline__ float bf2f(unsigned short u) {
    return __builtin_bit_cast(float, (unsigned)u << 16);
}
static __device__ __forceinline__ float rdlanef(float v, int l) {
    return __builtin_bit_cast(float, __builtin_amdgcn_readlane(__builtin_bit_cast(int, v), l));
}

// ---------------- helpers ----------------
__device__ __forceinline__ void ln_stats128(float v, float& mean, float& istd, float* red) {
    float s = v, s2 = v * v;
#pragma unroll
    for (int off = 32; off; off >>= 1) { s += __shfl_xor(s, off); s2 += __shfl_xor(s2, off); }
    int w = threadIdx.x >> 6;
    if ((threadIdx.x & 63) == 0) { red[w * 2] = s; red[w * 2 + 1] = s2; }
    __syncthreads();
    float ts = red[0] + red[2], ts2 = red[1] + red[3];
    mean = ts * (1.f / 128.f);
    float var = ts2 * (1.f / 128.f) - mean * mean;
    istd = rsqrtf(var + EPS);
    __syncthreads();
}

// ---------------- CSR build: bucketed counting sort ----------------
__global__ __launch_bounds__(256) void bucket_count(const int* __restrict__ dst,
                                                    int* __restrict__ bucket_cnt) {
    __shared__ int bcnt[256];
    int tid = threadIdx.x;
    bcnt[tid] = 0;
    __syncthreads();
    int base = blockIdx.x * CHUNK;
#pragma unroll
    for (int j = 0; j < 16; j++) {
        int d = dst[base + j * 256 + tid];
        atomicAdd(&bcnt[d >> 7], 1);
    }
    __syncthreads();
    atomicAdd(&bucket_cnt[tid], bcnt[tid]);
}

__global__ __launch_bounds__(256) void scan_buckets(const int* __restrict__ bucket_cnt,
                                                    int* __restrict__ bucket_base,
                                                    int* __restrict__ bucket_fill) {
    __shared__ int sc[256];
    int t = threadIdx.x;
    int c = bucket_cnt[t];
    sc[t] = c;
    __syncthreads();
    for (int off = 1; off < 256; off <<= 1) {
        int v = (t >= off) ? sc[t - off] : 0;
        __syncthreads();
        sc[t] += v;
        __syncthreads();
    }
    int ex = sc[t] - c;
    bucket_base[t] = ex;
    bucket_fill[t] = ex;
    if (t == 255) bucket_base[256] = sc[255];
}

__global__ __launch_bounds__(256) void bucket_scatter(const int* __restrict__ src,
                                                      const int* __restrict__ dst,
                                                      int* __restrict__ bucket_fill,
                                                      int* __restrict__ packed) {
    __shared__ int bcnt[256];
    __shared__ int lsc[256];
    __shared__ int delta[256];
    __shared__ int sorted[CHUNK];
    int tid = threadIdx.x;
    int base = blockIdx.x * CHUNK;
    int pk[16], bk[16], rk[16];
    bcnt[tid] = 0;
    __syncthreads();
#pragma unroll
    for (int j = 0; j < 16; j++) {
        int e = base + j * 256 + tid;
        int d = dst[e], s = src[e];
        pk[j] = (d << 15) | s;
        bk[j] = d >> 7;
    }
#pragma unroll
    for (int j = 0; j < 16; j++) rk[j] = atomicAdd(&bcnt[bk[j]], 1);
    __syncthreads();
    int cnt_t = bcnt[tid];
    lsc[tid] = cnt_t;
    __syncthreads();
    for (int off = 1; off < 256; off <<= 1) {
        int v = (tid >= off) ? lsc[tid - off] : 0;
        __syncthreads();
        lsc[tid] += v;
        __syncthreads();
    }
    int ls_t = lsc[tid] - cnt_t;
    __syncthreads();
    lsc[tid] = ls_t;
    int g = 0;
    if (cnt_t > 0) g = atomicAdd(&bucket_fill[tid], cnt_t);
    delta[tid] = g - ls_t;
    __syncthreads();
#pragma unroll
    for (int j = 0; j < 16; j++) sorted[lsc[bk[j]] + rk[j]] = pk[j];
    __syncthreads();
    for (int i = tid; i < CHUNK; i += 256) {
        int u = sorted[i];
        int b2 = u >> 22;
        packed[delta[b2] + i] = u;
    }
}

__global__ __launch_bounds__(256) void csr_build(const int* __restrict__ bucket_base,
                                                 const int* __restrict__ packed,
                                                 int* __restrict__ srcs,
                                                 int* __restrict__ row_ptr,
                                                 float* __restrict__ dis) {
    __shared__ int ncnt[128];
    __shared__ int sc[128];
    __shared__ int fill[128];
    __shared__ int outl[BCAP];
    int b = blockIdx.x, tid = threadIdx.x;
    int c0 = bucket_base[b], c1 = bucket_base[b + 1];
    int cnt = c1 - c0;
    if (tid < 128) ncnt[tid] = 0;
    __syncthreads();
    for (int i = tid; i < cnt; i += 256) {
        int u = packed[c0 + i];
        atomicAdd(&ncnt[(u >> 15) & 127], 1);
    }
    __syncthreads();
    int c = (tid < 128) ? ncnt[tid] : 0;
    if (tid < 128) sc[tid] = c;
    __syncthreads();
    for (int off = 1; off < 128; off <<= 1) {
        int v = (tid < 128 && tid >= off) ? sc[tid - off] : 0;
        __syncthreads();
        if (tid < 128) sc[tid] += v;
        __syncthreads();
    }
    if (tid < 128) {
        int ex = sc[tid] - c;
        fill[tid] = ex;
        int node = b * 128 + tid;
        row_ptr[node] = c0 + ex;
        dis[node] = rsqrtf((float)(c + 1));
    }
    if (b == 255 && tid == 0) row_ptr[N_NODES] = c1;
    __syncthreads();
    if (cnt <= BCAP) {
        for (int i = tid; i < cnt; i += 256) {
            int u = packed[c0 + i];
            int p = atomicAdd(&fill[(u >> 15) & 127], 1);
            outl[p] = u & 32767;
        }
        __syncthreads();
        for (int i = tid; i < cnt; i += 256) srcs[c0 + i] = outl[i];
    } else {
        for (int i = tid; i < cnt; i += 256) {
            int u = packed[c0 + i];
            int p = atomicAdd(&fill[(u >> 15) & 127], 1);
            srcs[c0 + p] = u & 32767;
        }
    }
}

// ---------------- weight prep ----------------
__global__ __launch_bounds__(256) void prep_weights(const float* __restrict__ Wc,
                                                    const float* __restrict__ Wq,
                                                    const float* __restrict__ Wk,
                                                    const float* __restrict__ Wv,
                                                    const float* __restrict__ Wo,
                                                    const float* __restrict__ bq,
                                                    const float* __restrict__ bk,
                                                    const float* __restrict__ bv,
                                                    unsigned short* __restrict__ Wpk,
                                                    float* __restrict__ bT) {
    int m = blockIdx.y;
    int idx = blockIdx.x * 256 + threadIdx.x;   // 0..16383
    int j = idx & 3, ln = (idx >> 2) & 63, kt = (idx >> 8) & 7, jt = (idx >> 11) & 7;
    int k = kt * 16 + (ln >> 4) * 4 + j;
    int col = jt * 16 + (ln & 15);
    float val;
    if (m < 3) val = Wc[m * 16384 + k * 128 + col];
    else {
        const float* W = (m == 3) ? Wq : (m == 4) ? Wk : (m == 5) ? Wv : Wo;
        val = W[col * 128 + k];
    }
    Wpk[m * 16384 + idx] = bfbits(val);
    if (m >= 3 && m < 6 && idx < 128) {
        const float* bs = (m == 3) ? bq : (m == 4) ? bk : bv;
        bT[(m - 3) * 128 + idx] = bs[idx];
    }
}

// ---------------- input projection + LN + ReLU -> bf16 (v1: block-per-node) ----------------
__global__ __launch_bounds__(128) void input_proj(const float* __restrict__ x,
                                                  const float* __restrict__ W,
                                                  const float* __restrict__ b,
                                                  const float* __restrict__ g,
                                                  const float* __restrict__ be,
                                                  unsigned short* __restrict__ h16) {
    int n = blockIdx.x, j = threadIdx.x;
    __shared__ float xs[15];
    __shared__ float red[4];
    if (j < 15) xs[j] = x[n * 15 + j];
    __syncthreads();
    float acc = b[j];
#pragma unroll
    for (int k = 0; k < 15; k++) acc += xs[k] * W[k * 128 + j];
    float m, is;
    ln_stats128(acc, m, is, red);
    float y = (acc - m) * is * g[j] + be[j];
    h16[(long)n * 128 + j] = bfbits(fmaxf(y, 0.f));
}

// ---------------- MFMA GEMM ----------------
template <int MODE>
__device__ __forceinline__ void gemm_mfma_body(const unsigned short* __restrict__ in16,
                                               const unsigned short* __restrict__ Wpk,
                                               const float* __restrict__ bias,
                                               const unsigned short* __restrict__ resid16,
                                               const float* __restrict__ gamma,
                                               const float* __restrict__ beta,
                                               unsigned short* __restrict__ out16) {
    __shared__ unsigned short Ws[16384];
    __shared__ unsigned short Hs[64][136];
    int tid = threadIdx.x;
    long base = (long)blockIdx.x * 64;
    {
        const uint4* s4 = (const uint4*)Wpk;
        uint4* d4 = (uint4*)Ws;
        for (int i = tid; i < 2048; i += 256) d4[i] = s4[i];
        const unsigned short* hsrc = in16 + base * 128;
        for (int i = tid; i < 1024; i += 256) {
            int r = i >> 4, c8 = i & 15;
            *(uint4*)&Hs[r][c8 * 8] = *(const uint4*)&hsrc[r * 128 + c8 * 8];
        }
    }
    __syncthreads();
    int wv = tid >> 6, lane = tid & 63;
    int ql = lane & 15, qg = lane >> 4;
    f32x4 acc[8];
#pragma unroll
    for (int jt = 0; jt < 8; jt++) acc[jt] = (f32x4){0.f, 0.f, 0.f, 0.f};
#pragma unroll
    for (int kt = 0; kt < 8; kt++) {
        bf16x4 af = *(const bf16x4*)&Hs[wv * 16 + ql][kt * 16 + qg * 4];
#pragma unroll
        for (int jt = 0; jt < 8; jt++) {
            bf16x4 bf = *(const bf16x4*)&Ws[((jt * 8 + kt) * 64 + lane) * 4];
            acc[jt] = __builtin_amdgcn_mfma_f32_16x16x16bf16_1k(af, bf, acc[jt], 0, 0, 0);
        }
    }
    if (MODE >= 1) {
#pragma unroll
        for (int jt = 0; jt < 8; jt++) {
            float bv = bias[jt * 16 + ql];
#pragma unroll
            for (int r = 0; r < 4; r++) acc[jt][r] += bv;
        }
    }
    if (MODE == 2) {
#pragma unroll
        for (int jt = 0; jt < 8; jt++)
#pragma unroll
            for (int r = 0; r < 4; r++)
                acc[jt][r] += bf2f(resid16[(base + wv * 16 + qg * 4 + r) * 128 + jt * 16 + ql]);
        float s[4], s2[4], mean[4], istd[4];
#pragma unroll
        for (int r = 0; r < 4; r++) { s[r] = 0.f; s2[r] = 0.f; }
#pragma unroll
        for (int jt = 0; jt < 8; jt++)
#pragma unroll
            for (int r = 0; r < 4; r++) { float v = acc[jt][r]; s[r] += v; s2[r] += v * v; }
#pragma unroll
        for (int off = 1; off < 16; off <<= 1)
#pragma unroll
            for (int r = 0; r < 4; r++) {
                s[r] += __shfl_xor(s[r], off);
                s2[r] += __shfl_xor(s2[r], off);
            }
#pragma unroll
        for (int r = 0; r < 4; r++) {
            mean[r] = s[r] * (1.f / 128.f);
            float var = s2[r] * (1.f / 128.f) - mean[r] * mean[r];
            istd[r] = rsqrtf(var + EPS);
        }
#pragma unroll
        for (int jt = 0; jt < 8; jt++) {
            float gv = gamma[jt * 16 + ql], bev = beta[jt * 16 + ql];
#pragma unroll
            for (int r = 0; r < 4; r++)
                acc[jt][r] = (acc[jt][r] - mean[r]) * istd[r] * gv + bev;
        }
    }
#pragma unroll
    for (int jt = 0; jt < 8; jt++)
#pragma unroll
        for (int r = 0; r < 4; r++)
            Hs[wv * 16 + qg * 4 + r][jt * 16 + ql] = bfbits(acc[jt][r]);
#pragma unroll
    for (int p = 0; p < 4; p++) {
        int rl = p * 4 + qg;
        uint4 v = *(const uint4*)&Hs[wv * 16 + rl][ql * 8];
        *(uint4*)&out16[(base + wv * 16 + rl) * 128 + ql * 8] = v;
    }
}

template <int MODE>
__global__ __launch_bounds__(256) void gemm_mfma(const unsigned short* __restrict__ in16,
                                                 const unsigned short* __restrict__ Wpk,
                                                 const float* __restrict__ bias,
                                                 const unsigned short* __restrict__ resid16,
                                                 const float* __restrict__ gamma,
                                                 const float* __restrict__ beta,
                                                 unsigned short* __restrict__ out16) {
    gemm_mfma_body<MODE>(in16, Wpk, bias, resid16, gamma, beta, out16);
}

__global__ __launch_bounds__(256) void gemm_qkv(const unsigned short* __restrict__ in16,
                                                const unsigned short* __restrict__ Wpk,
                                                const float* __restrict__ bT,
                                                unsigned short* __restrict__ outb) {
    int y = blockIdx.y;
    gemm_mfma_body<1>(in16, Wpk + (3 + y) * 16384, bT + y * 128, nullptr, nullptr, nullptr,
                      outb + (long)y * N_NODES * 128);
}

// ---------------- GCN aggregation v4: wave-per-node, 16-deep batched loads ----------
__global__ __launch_bounds__(256) void gcn_agg(const unsigned short* __restrict__ hW,
                                               const int* __restrict__ row_ptr,
                                               const int* __restrict__ srcs,
                                               const float* __restrict__ dis,
                                               const float* __restrict__ bias,
                                               const float* __restrict__ gamma,
                                               const float* __restrict__ beta,
                                               unsigned short* __restrict__ h16, int with_resid) {
    int wv = threadIdx.x >> 6, lane = threadIdx.x & 63;
    int n = blockIdx.x * 4 + wv;
    int r0 = row_ptr[n], r1 = row_ptr[n + 1];
    float dn = dis[n];
    unsigned su = *(const unsigned*)&hW[(long)n * 128 + lane * 2];
    float dnn = dn * dn;
    float a0 = bf2f((unsigned short)(su & 0xffff)) * dnn;
    float a1 = bf2f((unsigned short)(su >> 16)) * dnn;
    for (int b = r0; b < r1; b += 64) {
        int cnt = min(64, r1 - b);
        int sv = n;          // pad: valid (hot) address, zero coefficient
        float cv = 0.f;
        if (lane < cnt) {
            sv = srcs[b + lane];
            cv = dis[sv] * dn;
        }
        int cntR = (cnt + 15) & ~15;
        for (int j = 0; j < cntR; j += 16) {
            unsigned u[16];
#pragma unroll
            for (int t = 0; t < 16; t++) {
                int s = __builtin_amdgcn_readlane(sv, j + t);
                u[t] = *(const unsigned*)&hW[(long)s * 128 + lane * 2];
            }
#pragma unroll
            for (int t = 0; t < 16; t++) {
                float c = rdlanef(cv, j + t);
                a0 += bf2f((unsigned short)(u[t] & 0xffff)) * c;
                a1 += bf2f((unsigned short)(u[t] >> 16)) * c;
            }
        }
    }
    float2 bb = *(const float2*)&bias[lane * 2];
    a0 += bb.x;
    a1 += bb.y;
    float s = a0 + a1, s2 = a0 * a0 + a1 * a1;
#pragma unroll
    for (int off = 1; off < 64; off <<= 1) { s += __shfl_xor(s, off); s2 += __shfl_xor(s2, off); }
    float mean = s * (1.f / 128.f);
    float var = s2 * (1.f / 128.f) - mean * mean;
    float is = rsqrtf(var + EPS);
    float2 gg = *(const float2*)&gamma[lane * 2];
    float2 be2 = *(const float2*)&beta[lane * 2];
    float y0 = fmaxf((a0 - mean) * is * gg.x + be2.x, 0.f);
    float y1 = fmaxf((a1 - mean) * is * gg.y + be2.y, 0.f);
    if (with_resid) {
        unsigned ru = *(const unsigned*)&h16[(long)n * 128 + lane * 2];
        y0 += bf2f((unsigned short)(ru & 0xffff));
        y1 += bf2f((unsigned short)(ru >> 16));
    }
    unsigned outu = (unsigned)bfbits(y0) | ((unsigned)bfbits(y1) << 16);
    *(unsigned*)&h16[(long)n * 128 + lane * 2] = outu;
}

// ---------------- attention: MFMA (swapped QK^T), bf16 output ----------------
__global__ __launch_bounds__(256) void attention(const unsigned short* __restrict__ q16,
                                                 const unsigned short* __restrict__ k16,
                                                 const unsigned short* __restrict__ v16,
                                                 unsigned short* __restrict__ o16) {
    int g = blockIdx.x, hh = blockIdx.y;
    int tid = threadIdx.x;
    long gbase = ((long)g * NPG) * 128 + hh * 16;
    __shared__ unsigned short Ksh[256][24];
    __shared__ unsigned short Qsh[256][24];
    __shared__ unsigned short Vt[16][264];
    {
        const unsigned short* kp = k16 + gbase + (long)tid * 128;
        uint4 a = *(const uint4*)kp, b = *(const uint4*)(kp + 8);
        *(uint4*)&Ksh[tid][0] = a; *(uint4*)&Ksh[tid][8] = b;
        const unsigned short* qp = q16 + gbase + (long)tid * 128;
        uint4 c = *(const uint4*)qp, d = *(const uint4*)(qp + 8);
        *(uint4*)&Qsh[tid][0] = c; *(uint4*)&Qsh[tid][8] = d;
        const unsigned short* vp = v16 + gbase + (long)tid * 128;
#pragma unroll
        for (int dd = 0; dd < 16; dd++) Vt[dd][tid] = vp[dd];
    }
    __syncthreads();
    int wv = tid >> 6, lane = tid & 63;
    int qg = lane >> 4, ql = lane & 15;
    bf16x4 vfrag[16];
#pragma unroll
    for (int kt = 0; kt < 16; kt++)
        vfrag[kt] = *(const bf16x4*)&Vt[ql][kt * 16 + qg * 4];
    const float C = 0.36067376022224085f;   // 0.25 * log2(e)
    for (int qi = 0; qi < 4; qi++) {
        int qt = wv * 4 + qi;
        bf16x4 qfrag = *(const bf16x4*)&Qsh[qt * 16 + ql][qg * 4];
        float lsum = 0.f;
        bf16x4 pb[16];
        f32x4 z4 = {0.f, 0.f, 0.f, 0.f};
#pragma unroll
        for (int kt = 0; kt < 16; kt++) {
            bf16x4 kfrag = *(const bf16x4*)&Ksh[kt * 16 + ql][qg * 4];
            f32x4 s4 = __builtin_amdgcn_mfma_f32_16x16x16bf16_1k(kfrag, qfrag, z4, 0, 0, 0);
            bf16x4 pbk;
#pragma unroll
            for (int r = 0; r < 4; r++) {
                float pv = exp2f(s4[r] * C);
                lsum += pv;
                pbk[r] = (short)bfbits(pv);
            }
            pb[kt] = pbk;
        }
        f32x4 oacc = {0.f, 0.f, 0.f, 0.f};
#pragma unroll
        for (int kt = 0; kt < 16; kt++)
            oacc = __builtin_amdgcn_mfma_f32_16x16x16bf16_1k(vfrag[kt], pb[kt], oacc, 0, 0, 0);
        lsum += __shfl_xor(lsum, 16);
        lsum += __shfl_xor(lsum, 32);
        float inv = 1.f / lsum;
        unsigned short* op = o16 + gbase + (long)(qt * 16 + ql) * 128 + 4 * qg;
        ushort4 st;
        st.x = bfbits(oacc[0] * inv);
        st.y = bfbits(oacc[1] * inv);
        st.z = bfbits(oacc[2] * inv);
        st.w = bfbits(oacc[3] * inv);
        *(ushort4*)op = st;
    }
}

// ---------------- pooling ----------------
__global__ __launch_bounds__(256) void pool_kernel(const unsigned short* __restrict__ hg,
                                                   float* __restrict__ pooled) {
    int g = blockIdx.x;
    int lane = threadIdx.x & 63, grp = threadIdx.x >> 6;
    __shared__ float ssum[4][128];
    __shared__ float smax[4][128];
    float s0 = 0.f, s1 = 0.f, m0 = -1e30f, m1 = -1e30f;
    for (int i = grp * 64; i < grp * 64 + 64; i++) {
        unsigned u = *(const unsigned*)&hg[((long)g * NPG + i) * 128 + lane * 2];
        float v0 = bf2f((unsigned short)(u & 0xffff));
        float v1 = bf2f((unsigned short)(u >> 16));
        s0 += v0; s1 += v1;
        m0 = fmaxf(m0, v0); m1 = fmaxf(m1, v1);
    }
    ssum[grp][lane * 2] = s0; ssum[grp][lane * 2 + 1] = s1;
    smax[grp][lane * 2] = m0; smax[grp][lane * 2 + 1] = m1;
    __syncthreads();
    if (grp == 0) {
        for (int jj = lane; jj < 128; jj += 64) {
            float ts = ssum[0][jj] + ssum[1][jj] + ssum[2][jj] + ssum[3][jj];
            float tm = fmaxf(fmaxf(smax[0][jj], smax[1][jj]), fmaxf(smax[2][jj], smax[3][jj]));
            pooled[g * 384 + jj] = ts * (1.f / 256.f);
            pooled[g * 384 + 128 + jj] = tm;
            pooled[g * 384 + 256 + jj] = ts;
        }
    }
}

// ---------------- classifier ----------------
__global__ __launch_bounds__(128) void classifier(const float* __restrict__ pooled,
                                                  const float* __restrict__ W1, const float* __restrict__ b1,
                                                  const float* __restrict__ g1, const float* __restrict__ be1,
                                                  const float* __restrict__ W2, const float* __restrict__ b2,
                                                  const float* __restrict__ W3, const float* __restrict__ b3,
                                                  float* __restrict__ out) {
    int g = blockIdx.x, j = threadIdx.x;
    __shared__ float pl[384];
    __shared__ float z1s[128];
    __shared__ float z2s[64];
    __shared__ float red[4];
    for (int i = j; i < 384; i += 128) pl[i] = pooled[g * 384 + i];
    __syncthreads();
    float acc = b1[j];
    for (int kk = 0; kk < 384; kk++) acc += pl[kk] * W1[kk * 128 + j];
    float m, is;
    ln_stats128(acc, m, is, red);
    float y = fmaxf((acc - m) * is * g1[j] + be1[j], 0.f);
    z1s[j] = y;
    __syncthreads();
    if (j < 64) {
        float a2 = b2[j];
        for (int kk = 0; kk < 128; kk++) a2 += z1s[kk] * W2[kk * 64 + j];
        z2s[j] = fmaxf(a2, 0.f);
    }
    __syncthreads();
    if (j < 64) {
        float vv = z2s[j];
        float p0 = vv * W3[j * 2];
        float p1 = vv * W3[j * 2 + 1];
#pragma unroll
        for (int off = 32; off; off >>= 1) { p0 += __shfl_xor(p0, off); p1 += __shfl_xor(p1, off); }
        if (j == 0) {
            out[g * 2] = p0 + b3[0];
            out[g * 2 + 1] = p1 + b3[1];
        }
    }
}

// ---------------- launch ----------------
extern "C" void kernel_launch(void* const* d_in, const int* in_sizes, int n_in,
                              void* d_out, int out_size, void* d_ws, size_t ws_size,
                              hipStream_t stream) {
    const float* x = (const float*)d_in[0];
    const int* ei = (const int*)d_in[1];
    const float* W_in = (const float*)d_in[3];
    const float* b_in = (const float*)d_in[4];
    const float* g_in = (const float*)d_in[5];
    const float* be_in = (const float*)d_in[6];
    const float* Wc = (const float*)d_in[7];
    const float* bc = (const float*)d_in[8];
    const float* gn = (const float*)d_in[9];
    const float* bn = (const float*)d_in[10];
    const float* Wq = (const float*)d_in[11];
    const float* bq = (const float*)d_in[12];
    const float* Wk = (const float*)d_in[13];
    const float* bk = (const float*)d_in[14];
    const float* Wv = (const float*)d_in[15];
    const float* bv = (const float*)d_in[16];
    const float* Wo = (const float*)d_in[17];
    const float* bo = (const float*)d_in[18];
    const float* ga = (const float*)d_in[19];
    const float* ba = (const float*)d_in[20];
    const float* W1 = (const float*)d_in[21];
    const float* b1 = (const float*)d_in[22];
    const float* g1 = (const float*)d_in[23];
    const float* be1 = (const float*)d_in[24];
    const float* W2 = (const float*)d_in[25];
    const float* b2 = (const float*)d_in[26];
    const float* W3 = (const float*)d_in[27];
    const float* b3 = (const float*)d_in[28];
    float* out = (float*)d_out;

    const long NF = (long)N_NODES * 128;
    unsigned char* wsb = (unsigned char*)d_ws;
    const size_t MB = 1 << 20;
    unsigned short* h16 = (unsigned short*)(wsb);             // 8MB
    unsigned short* hw16 = (unsigned short*)(wsb + 8 * MB);   // 8MB
    unsigned short* qkv16 = (unsigned short*)(wsb + 16 * MB); // 24MB
    unsigned short* o16 = (unsigned short*)(wsb + 40 * MB);   // 8MB
    unsigned short* hg16 = (unsigned short*)(wsb + 48 * MB);  // 8MB
    unsigned short* Wpk = (unsigned short*)(wsb + 56 * MB);   // 224KB
    int* packed = (int*)(wsb + 57 * MB);                      // 4MB
    int* srcs = (int*)(wsb + 61 * MB);                        // 4MB
    int* row_ptr = (int*)(wsb + 65 * MB);                     // 128KB+4
    float* dis = (float*)(wsb + 66 * MB);                     // 128KB
    float* bT = (float*)(wsb + 67 * MB);                      // 1.5KB
    float* pooled = (float*)(wsb + 67 * MB + 4096);           // 192KB
    int* bucket_cnt = (int*)(wsb + 68 * MB);                  // 256
    int* bucket_base = bucket_cnt + 256;                      // 257
    int* bucket_fill = bucket_base + 257;                     // 256

    const int* e_src = ei;
    const int* e_dst = ei + E_EDGES;

    hipMemsetAsync(bucket_cnt, 0, 256 * sizeof(int), stream);
    prep_weights<<<dim3(64, 7), 256, 0, stream>>>(Wc, Wq, Wk, Wv, Wo, bq, bk, bv, Wpk, bT);
    bucket_count<<<E_EDGES / CHUNK, 256, 0, stream>>>(e_dst, bucket_cnt);
    scan_buckets<<<1, 256, 0, stream>>>(bucket_cnt, bucket_base, bucket_fill);
    bucket_scatter<<<E_EDGES / CHUNK, 256, 0, stream>>>(e_src, e_dst, bucket_fill, packed);
    csr_build<<<256, 256, 0, stream>>>(bucket_base, packed, srcs, row_ptr, dis);

    input_proj<<<N_NODES, 128, 0, stream>>>(x, W_in, b_in, g_in, be_in, h16);

    for (int i = 0; i < 3; i++) {
        gemm_mfma<0><<<N_NODES / 64, 256, 0, stream>>>(h16, Wpk + i * 16384, nullptr, nullptr,
                                                       nullptr, nullptr, hw16);
        gcn_agg<<<N_NODES / 4, 256, 0, stream>>>(hw16, row_ptr, srcs, dis, bc + i * 128,
                                                 gn + i * 128, bn + i * 128, h16, i > 0);
    }

    gemm_qkv<<<dim3(N_NODES / 64, 3), 256, 0, stream>>>(h16, Wpk, bT, qkv16);

    attention<<<dim3(G_GRAPHS, NH), 256, 0, stream>>>(qkv16, qkv16 + NF, qkv16 + 2 * NF, o16);

    gemm_mfma<2><<<N_NODES / 64, 256, 0, stream>>>(o16, Wpk + 6 * 16384, bo, h16, ga, ba, hg16);

    pool_kernel<<<G_GRAPHS, 256, 0, stream>>>(hg16, pooled);
    classifier<<<G_GRAPHS, 128, 0, stream>>>(pooled, W1, b1, g1, be1, W2, b2, W3, b3, out);
}

// Round 10
// 352.551 us; speedup vs baseline: 1.0865x; 1.0409x over previous
//
#include <hip/hip_runtime.h>
#include <hip/hip_bf16.h>

#define N_NODES 32768
#define E_EDGES 1048576
#define HID 128
#define G_GRAPHS 128
#define NPG 256
#define NH 8
#define DH 16
#define EPS 1e-5f
#define CHUNK 4096
#define BCAP 8192
#define BSTRIDE 16384   // fixed region per bucket (mean fill 4096, sigma ~64)

typedef __attribute__((ext_vector_type(4))) float f32x4;
typedef __attribute__((ext_vector_type(4))) short bf16x4;

static __device__ __forceinline__ unsigned short bfbits(float f) {
    return __builtin_bit_cast(unsigned short, __float2bfloat16(f));
}
static __device__ __forceinline__ float bf2f(unsigned short u) {
    return __builtin_bit_cast(float, (unsigned)u << 16);
}
static __device__ __forceinline__ float rdlanef(float v, int l) {
    return __builtin_bit_cast(float, __builtin_amdgcn_readlane(__builtin_bit_cast(int, v), l));
}

// ---------------- helpers ----------------
__device__ __forceinline__ void ln_stats128(float v, float& mean, float& istd, float* red) {
    float s = v, s2 = v * v;
#pragma unroll
    for (int off = 32; off; off >>= 1) { s += __shfl_xor(s, off); s2 += __shfl_xor(s2, off); }
    int w = threadIdx.x >> 6;
    if ((threadIdx.x & 63) == 0) { red[w * 2] = s; red[w * 2 + 1] = s2; }
    __syncthreads();
    float ts = red[0] + red[2], ts2 = red[1] + red[3];
    mean = ts * (1.f / 128.f);
    float var = ts2 * (1.f / 128.f) - mean * mean;
    istd = rsqrtf(var + EPS);
    __syncthreads();
}

// ---------------- CSR build v2: fixed-stride buckets (2 kernels) ----------------
// bucket b = dst>>7 owns region [b*BSTRIDE, b*BSTRIDE+cnt). bucket_fill (zeroed)
// doubles as the reservation cursor and, after scatter, the final per-bucket count.
__global__ __launch_bounds__(256) void bucket_scatter(const int* __restrict__ src,
                                                      const int* __restrict__ dst,
                                                      int* __restrict__ bucket_fill,
                                                      int* __restrict__ packed) {
    __shared__ int bcnt[256];
    __shared__ int lsc[256];
    __shared__ int delta[256];
    __shared__ int sorted[CHUNK];
    int tid = threadIdx.x;
    int base = blockIdx.x * CHUNK;
    int pk[16], bk[16], rk[16];
    bcnt[tid] = 0;
    __syncthreads();
#pragma unroll
    for (int j = 0; j < 16; j++) {
        int e = base + j * 256 + tid;    // coalesced
        int d = dst[e], s = src[e];
        pk[j] = (d << 15) | s;           // 30 bits
        bk[j] = d >> 7;
    }
#pragma unroll
    for (int j = 0; j < 16; j++) rk[j] = atomicAdd(&bcnt[bk[j]], 1);
    __syncthreads();
    int cnt_t = bcnt[tid];
    lsc[tid] = cnt_t;
    __syncthreads();
    for (int off = 1; off < 256; off <<= 1) {
        int v = (tid >= off) ? lsc[tid - off] : 0;
        __syncthreads();
        lsc[tid] += v;
        __syncthreads();
    }
    int ls_t = lsc[tid] - cnt_t;   // exclusive local offset of bucket tid
    __syncthreads();
    lsc[tid] = ls_t;
    int g = 0;
    if (cnt_t > 0) g = atomicAdd(&bucket_fill[tid], cnt_t);   // pos within bucket region
    delta[tid] = tid * BSTRIDE + g - ls_t;
    __syncthreads();
#pragma unroll
    for (int j = 0; j < 16; j++) sorted[lsc[bk[j]] + rk[j]] = pk[j];
    __syncthreads();
    for (int i = tid; i < CHUNK; i += 256) {
        int u = sorted[i];
        int b2 = u >> 22;              // = dst>>7
        packed[delta[b2] + i] = u;     // contiguous runs per bucket
    }
}

__global__ __launch_bounds__(256) void csr_build(const int* __restrict__ bucket_fill,
                                                 const int* __restrict__ packed,
                                                 int* __restrict__ srcs,
                                                 int* __restrict__ row_ptr,
                                                 int* __restrict__ row_end,
                                                 float* __restrict__ dis) {
    __shared__ int ncnt[128];
    __shared__ int sc[128];
    __shared__ int fill[128];
    __shared__ int outl[BCAP];
    int b = blockIdx.x, tid = threadIdx.x;
    int c0 = b * BSTRIDE;
    int cnt = bucket_fill[b];
    if (tid < 128) ncnt[tid] = 0;
    __syncthreads();
    for (int i = tid; i < cnt; i += 256) {
        int u = packed[c0 + i];
        atomicAdd(&ncnt[(u >> 15) & 127], 1);
    }
    __syncthreads();
    int c = (tid < 128) ? ncnt[tid] : 0;
    if (tid < 128) sc[tid] = c;
    __syncthreads();
    for (int off = 1; off < 128; off <<= 1) {
        int v = (tid < 128 && tid >= off) ? sc[tid - off] : 0;
        __syncthreads();
        if (tid < 128) sc[tid] += v;
        __syncthreads();
    }
    if (tid < 128) {
        int ex = sc[tid] - c;
        fill[tid] = ex;
        int node = b * 128 + tid;
        row_ptr[node] = c0 + ex;
        row_end[node] = c0 + ex + c;
        dis[node] = rsqrtf((float)(c + 1));   // deg includes self-loop
    }
    __syncthreads();
    if (cnt <= BCAP) {
        for (int i = tid; i < cnt; i += 256) {
            int u = packed[c0 + i];
            int p = atomicAdd(&fill[(u >> 15) & 127], 1);
            outl[p] = u & 32767;
        }
        __syncthreads();
        for (int i = tid; i < cnt; i += 256) srcs[c0 + i] = outl[i];  // coalesced
    } else {
        for (int i = tid; i < cnt; i += 256) {
            int u = packed[c0 + i];
            int p = atomicAdd(&fill[(u >> 15) & 127], 1);
            srcs[c0 + p] = u & 32767;
        }
    }
}

// ---------------- weight prep ----------------
__global__ __launch_bounds__(256) void prep_weights(const float* __restrict__ Wc,
                                                    const float* __restrict__ Wq,
                                                    const float* __restrict__ Wk,
                                                    const float* __restrict__ Wv,
                                                    const float* __restrict__ Wo,
                                                    const float* __restrict__ bq,
                                                    const float* __restrict__ bk,
                                                    const float* __restrict__ bv,
                                                    unsigned short* __restrict__ Wpk,
                                                    float* __restrict__ bT) {
    int m = blockIdx.y;
    int idx = blockIdx.x * 256 + threadIdx.x;   // 0..16383
    int j = idx & 3, ln = (idx >> 2) & 63, kt = (idx >> 8) & 7, jt = (idx >> 11) & 7;
    int k = kt * 16 + (ln >> 4) * 4 + j;
    int col = jt * 16 + (ln & 15);
    float val;
    if (m < 3) val = Wc[m * 16384 + k * 128 + col];
    else {
        const float* W = (m == 3) ? Wq : (m == 4) ? Wk : (m == 5) ? Wv : Wo;
        val = W[col * 128 + k];
    }
    Wpk[m * 16384 + idx] = bfbits(val);
    if (m >= 3 && m < 6 && idx < 128) {
        const float* bs = (m == 3) ? bq : (m == 4) ? bk : bv;
        bT[(m - 3) * 128 + idx] = bs[idx];
    }
}

// ---------------- input projection + LN + ReLU -> bf16 (block-per-node) ----------------
__global__ __launch_bounds__(128) void input_proj(const float* __restrict__ x,
                                                  const float* __restrict__ W,
                                                  const float* __restrict__ b,
                                                  const float* __restrict__ g,
                                                  const float* __restrict__ be,
                                                  unsigned short* __restrict__ h16) {
    int n = blockIdx.x, j = threadIdx.x;
    __shared__ float xs[15];
    __shared__ float red[4];
    if (j < 15) xs[j] = x[n * 15 + j];
    __syncthreads();
    float acc = b[j];
#pragma unroll
    for (int k = 0; k < 15; k++) acc += xs[k] * W[k * 128 + j];
    float m, is;
    ln_stats128(acc, m, is, red);
    float y = (acc - m) * is * g[j] + be[j];
    h16[(long)n * 128 + j] = bfbits(fmaxf(y, 0.f));
}

// ---------------- MFMA GEMM ----------------
template <int MODE>
__device__ __forceinline__ void gemm_mfma_body(const unsigned short* __restrict__ in16,
                                               const unsigned short* __restrict__ Wpk,
                                               const float* __restrict__ bias,
                                               const unsigned short* __restrict__ resid16,
                                               const float* __restrict__ gamma,
                                               const float* __restrict__ beta,
                                               unsigned short* __restrict__ out16) {
    __shared__ unsigned short Ws[16384];
    __shared__ unsigned short Hs[64][136];
    int tid = threadIdx.x;
    long base = (long)blockIdx.x * 64;
    {
        const uint4* s4 = (const uint4*)Wpk;
        uint4* d4 = (uint4*)Ws;
        for (int i = tid; i < 2048; i += 256) d4[i] = s4[i];
        const unsigned short* hsrc = in16 + base * 128;
        for (int i = tid; i < 1024; i += 256) {
            int r = i >> 4, c8 = i & 15;
            *(uint4*)&Hs[r][c8 * 8] = *(const uint4*)&hsrc[r * 128 + c8 * 8];
        }
    }
    __syncthreads();
    int wv = tid >> 6, lane = tid & 63;
    int ql = lane & 15, qg = lane >> 4;
    f32x4 acc[8];
#pragma unroll
    for (int jt = 0; jt < 8; jt++) acc[jt] = (f32x4){0.f, 0.f, 0.f, 0.f};
#pragma unroll
    for (int kt = 0; kt < 8; kt++) {
        bf16x4 af = *(const bf16x4*)&Hs[wv * 16 + ql][kt * 16 + qg * 4];
#pragma unroll
        for (int jt = 0; jt < 8; jt++) {
            bf16x4 bf = *(const bf16x4*)&Ws[((jt * 8 + kt) * 64 + lane) * 4];
            acc[jt] = __builtin_amdgcn_mfma_f32_16x16x16bf16_1k(af, bf, acc[jt], 0, 0, 0);
        }
    }
    if (MODE >= 1) {
#pragma unroll
        for (int jt = 0; jt < 8; jt++) {
            float bv = bias[jt * 16 + ql];
#pragma unroll
            for (int r = 0; r < 4; r++) acc[jt][r] += bv;
        }
    }
    if (MODE == 2) {
#pragma unroll
        for (int jt = 0; jt < 8; jt++)
#pragma unroll
            for (int r = 0; r < 4; r++)
                acc[jt][r] += bf2f(resid16[(base + wv * 16 + qg * 4 + r) * 128 + jt * 16 + ql]);
        float s[4], s2[4], mean[4], istd[4];
#pragma unroll
        for (int r = 0; r < 4; r++) { s[r] = 0.f; s2[r] = 0.f; }
#pragma unroll
        for (int jt = 0; jt < 8; jt++)
#pragma unroll
            for (int r = 0; r < 4; r++) { float v = acc[jt][r]; s[r] += v; s2[r] += v * v; }
#pragma unroll
        for (int off = 1; off < 16; off <<= 1)
#pragma unroll
            for (int r = 0; r < 4; r++) {
                s[r] += __shfl_xor(s[r], off);
                s2[r] += __shfl_xor(s2[r], off);
            }
#pragma unroll
        for (int r = 0; r < 4; r++) {
            mean[r] = s[r] * (1.f / 128.f);
            float var = s2[r] * (1.f / 128.f) - mean[r] * mean[r];
            istd[r] = rsqrtf(var + EPS);
        }
#pragma unroll
        for (int jt = 0; jt < 8; jt++) {
            float gv = gamma[jt * 16 + ql], bev = beta[jt * 16 + ql];
#pragma unroll
            for (int r = 0; r < 4; r++)
                acc[jt][r] = (acc[jt][r] - mean[r]) * istd[r] * gv + bev;
        }
    }
#pragma unroll
    for (int jt = 0; jt < 8; jt++)
#pragma unroll
        for (int r = 0; r < 4; r++)
            Hs[wv * 16 + qg * 4 + r][jt * 16 + ql] = bfbits(acc[jt][r]);
#pragma unroll
    for (int p = 0; p < 4; p++) {
        int rl = p * 4 + qg;
        uint4 v = *(const uint4*)&Hs[wv * 16 + rl][ql * 8];
        *(uint4*)&out16[(base + wv * 16 + rl) * 128 + ql * 8] = v;
    }
}

template <int MODE>
__global__ __launch_bounds__(256) void gemm_mfma(const unsigned short* __restrict__ in16,
                                                 const unsigned short* __restrict__ Wpk,
                                                 const float* __restrict__ bias,
                                                 const unsigned short* __restrict__ resid16,
                                                 const float* __restrict__ gamma,
                                                 const float* __restrict__ beta,
                                                 unsigned short* __restrict__ out16) {
    gemm_mfma_body<MODE>(in16, Wpk, bias, resid16, gamma, beta, out16);
}

__global__ __launch_bounds__(256) void gemm_qkv(const unsigned short* __restrict__ in16,
                                                const unsigned short* __restrict__ Wpk,
                                                const float* __restrict__ bT,
                                                unsigned short* __restrict__ outb) {
    int y = blockIdx.y;
    gemm_mfma_body<1>(in16, Wpk + (3 + y) * 16384, bT + y * 128, nullptr, nullptr, nullptr,
                      outb + (long)y * N_NODES * 128);
}

// ---------------- GCN aggregation v4: wave-per-node, 16-deep batched loads ----------
__global__ __launch_bounds__(256) void gcn_agg(const unsigned short* __restrict__ hW,
                                               const int* __restrict__ row_ptr,
                                               const int* __restrict__ row_end,
                                               const int* __restrict__ srcs,
                                               const float* __restrict__ dis,
                                               const float* __restrict__ bias,
                                               const float* __restrict__ gamma,
                                               const float* __restrict__ beta,
                                               unsigned short* __restrict__ h16, int with_resid) {
    int wv = threadIdx.x >> 6, lane = threadIdx.x & 63;
    int n = blockIdx.x * 4 + wv;
    int r0 = row_ptr[n], r1 = row_end[n];
    float dn = dis[n];
    unsigned su = *(const unsigned*)&hW[(long)n * 128 + lane * 2];
    float dnn = dn * dn;
    float a0 = bf2f((unsigned short)(su & 0xffff)) * dnn;
    float a1 = bf2f((unsigned short)(su >> 16)) * dnn;
    for (int b = r0; b < r1; b += 64) {
        int cnt = min(64, r1 - b);
        int sv = n;          // pad: valid (hot) address, zero coefficient
        float cv = 0.f;
        if (lane < cnt) {
            sv = srcs[b + lane];
            cv = dis[sv] * dn;
        }
        int cntR = (cnt + 15) & ~15;
        for (int j = 0; j < cntR; j += 16) {
            unsigned u[16];
#pragma unroll
            for (int t = 0; t < 16; t++) {
                int s = __builtin_amdgcn_readlane(sv, j + t);
                u[t] = *(const unsigned*)&hW[(long)s * 128 + lane * 2];
            }
#pragma unroll
            for (int t = 0; t < 16; t++) {
                float c = rdlanef(cv, j + t);
                a0 += bf2f((unsigned short)(u[t] & 0xffff)) * c;
                a1 += bf2f((unsigned short)(u[t] >> 16)) * c;
            }
        }
    }
    float2 bb = *(const float2*)&bias[lane * 2];
    a0 += bb.x;
    a1 += bb.y;
    float s = a0 + a1, s2 = a0 * a0 + a1 * a1;
#pragma unroll
    for (int off = 1; off < 64; off <<= 1) { s += __shfl_xor(s, off); s2 += __shfl_xor(s2, off); }
    float mean = s * (1.f / 128.f);
    float var = s2 * (1.f / 128.f) - mean * mean;
    float is = rsqrtf(var + EPS);
    float2 gg = *(const float2*)&gamma[lane * 2];
    float2 be2 = *(const float2*)&beta[lane * 2];
    float y0 = fmaxf((a0 - mean) * is * gg.x + be2.x, 0.f);
    float y1 = fmaxf((a1 - mean) * is * gg.y + be2.y, 0.f);
    if (with_resid) {
        unsigned ru = *(const unsigned*)&h16[(long)n * 128 + lane * 2];
        y0 += bf2f((unsigned short)(ru & 0xffff));
        y1 += bf2f((unsigned short)(ru >> 16));
    }
    unsigned outu = (unsigned)bfbits(y0) | ((unsigned)bfbits(y1) << 16);
    *(unsigned*)&h16[(long)n * 128 + lane * 2] = outu;
}

// ---------------- attention: MFMA (swapped QK^T), bf16 output ----------------
__global__ __launch_bounds__(256) void attention(const unsigned short* __restrict__ q16,
                                                 const unsigned short* __restrict__ k16,
                                                 const unsigned short* __restrict__ v16,
                                                 unsigned short* __restrict__ o16) {
    int g = blockIdx.x, hh = blockIdx.y;
    int tid = threadIdx.x;
    long gbase = ((long)g * NPG) * 128 + hh * 16;
    __shared__ unsigned short Ksh[256][24];
    __shared__ unsigned short Qsh[256][24];
    __shared__ unsigned short Vt[16][264];
    {
        const unsigned short* kp = k16 + gbase + (long)tid * 128;
        uint4 a = *(const uint4*)kp, b = *(const uint4*)(kp + 8);
        *(uint4*)&Ksh[tid][0] = a; *(uint4*)&Ksh[tid][8] = b;
        const unsigned short* qp = q16 + gbase + (long)tid * 128;
        uint4 c = *(const uint4*)qp, d = *(const uint4*)(qp + 8);
        *(uint4*)&Qsh[tid][0] = c; *(uint4*)&Qsh[tid][8] = d;
        const unsigned short* vp = v16 + gbase + (long)tid * 128;
#pragma unroll
        for (int dd = 0; dd < 16; dd++) Vt[dd][tid] = vp[dd];
    }
    __syncthreads();
    int wv = tid >> 6, lane = tid & 63;
    int qg = lane >> 4, ql = lane & 15;
    bf16x4 vfrag[16];
#pragma unroll
    for (int kt = 0; kt < 16; kt++)
        vfrag[kt] = *(const bf16x4*)&Vt[ql][kt * 16 + qg * 4];
    const float C = 0.36067376022224085f;   // 0.25 * log2(e)
    for (int qi = 0; qi < 4; qi++) {
        int qt = wv * 4 + qi;
        bf16x4 qfrag = *(const bf16x4*)&Qsh[qt * 16 + ql][qg * 4];
        float lsum = 0.f;
        bf16x4 pb[16];
        f32x4 z4 = {0.f, 0.f, 0.f, 0.f};
#pragma unroll
        for (int kt = 0; kt < 16; kt++) {
            bf16x4 kfrag = *(const bf16x4*)&Ksh[kt * 16 + ql][qg * 4];
            f32x4 s4 = __builtin_amdgcn_mfma_f32_16x16x16bf16_1k(kfrag, qfrag, z4, 0, 0, 0);
            bf16x4 pbk;
#pragma unroll
            for (int r = 0; r < 4; r++) {
                float pv = exp2f(s4[r] * C);
                lsum += pv;
                pbk[r] = (short)bfbits(pv);
            }
            pb[kt] = pbk;
        }
        f32x4 oacc = {0.f, 0.f, 0.f, 0.f};
#pragma unroll
        for (int kt = 0; kt < 16; kt++)
            oacc = __builtin_amdgcn_mfma_f32_16x16x16bf16_1k(vfrag[kt], pb[kt], oacc, 0, 0, 0);
        lsum += __shfl_xor(lsum, 16);
        lsum += __shfl_xor(lsum, 32);
        float inv = 1.f / lsum;
        unsigned short* op = o16 + gbase + (long)(qt * 16 + ql) * 128 + 4 * qg;
        ushort4 st;
        st.x = bfbits(oacc[0] * inv);
        st.y = bfbits(oacc[1] * inv);
        st.z = bfbits(oacc[2] * inv);
        st.w = bfbits(oacc[3] * inv);
        *(ushort4*)op = st;
    }
}

// ---------------- pooling ----------------
__global__ __launch_bounds__(256) void pool_kernel(const unsigned short* __restrict__ hg,
                                                   float* __restrict__ pooled) {
    int g = blockIdx.x;
    int lane = threadIdx.x & 63, grp = threadIdx.x >> 6;
    __shared__ float ssum[4][128];
    __shared__ float smax[4][128];
    float s0 = 0.f, s1 = 0.f, m0 = -1e30f, m1 = -1e30f;
    for (int i = grp * 64; i < grp * 64 + 64; i++) {
        unsigned u = *(const unsigned*)&hg[((long)g * NPG + i) * 128 + lane * 2];
        float v0 = bf2f((unsigned short)(u & 0xffff));
        float v1 = bf2f((unsigned short)(u >> 16));
        s0 += v0; s1 += v1;
        m0 = fmaxf(m0, v0); m1 = fmaxf(m1, v1);
    }
    ssum[grp][lane * 2] = s0; ssum[grp][lane * 2 + 1] = s1;
    smax[grp][lane * 2] = m0; smax[grp][lane * 2 + 1] = m1;
    __syncthreads();
    if (grp == 0) {
        for (int jj = lane; jj < 128; jj += 64) {
            float ts = ssum[0][jj] + ssum[1][jj] + ssum[2][jj] + ssum[3][jj];
            float tm = fmaxf(fmaxf(smax[0][jj], smax[1][jj]), fmaxf(smax[2][jj], smax[3][jj]));
            pooled[g * 384 + jj] = ts * (1.f / 256.f);
            pooled[g * 384 + 128 + jj] = tm;
            pooled[g * 384 + 256 + jj] = ts;
        }
    }
}

// ---------------- classifier ----------------
__global__ __launch_bounds__(128) void classifier(const float* __restrict__ pooled,
                                                  const float* __restrict__ W1, const float* __restrict__ b1,
                                                  const float* __restrict__ g1, const float* __restrict__ be1,
                                                  const float* __restrict__ W2, const float* __restrict__ b2,
                                                  const float* __restrict__ W3, const float* __restrict__ b3,
                                                  float* __restrict__ out) {
    int g = blockIdx.x, j = threadIdx.x;
    __shared__ float pl[384];
    __shared__ float z1s[128];
    __shared__ float z2s[64];
    __shared__ float red[4];
    for (int i = j; i < 384; i += 128) pl[i] = pooled[g * 384 + i];
    __syncthreads();
    float acc = b1[j];
    for (int kk = 0; kk < 384; kk++) acc += pl[kk] * W1[kk * 128 + j];
    float m, is;
    ln_stats128(acc, m, is, red);
    float y = fmaxf((acc - m) * is * g1[j] + be1[j], 0.f);
    z1s[j] = y;
    __syncthreads();
    if (j < 64) {
        float a2 = b2[j];
        for (int kk = 0; kk < 128; kk++) a2 += z1s[kk] * W2[kk * 64 + j];
        z2s[j] = fmaxf(a2, 0.f);
    }
    __syncthreads();
    if (j < 64) {
        float vv = z2s[j];
        float p0 = vv * W3[j * 2];
        float p1 = vv * W3[j * 2 + 1];
#pragma unroll
        for (int off = 32; off; off >>= 1) { p0 += __shfl_xor(p0, off); p1 += __shfl_xor(p1, off); }
        if (j == 0) {
            out[g * 2] = p0 + b3[0];
            out[g * 2 + 1] = p1 + b3[1];
        }
    }
}

// ---------------- launch ----------------
extern "C" void kernel_launch(void* const* d_in, const int* in_sizes, int n_in,
                              void* d_out, int out_size, void* d_ws, size_t ws_size,
                              hipStream_t stream) {
    const float* x = (const float*)d_in[0];
    const int* ei = (const int*)d_in[1];
    const float* W_in = (const float*)d_in[3];
    const float* b_in = (const float*)d_in[4];
    const float* g_in = (const float*)d_in[5];
    const float* be_in = (const float*)d_in[6];
    const float* Wc = (const float*)d_in[7];
    const float* bc = (const float*)d_in[8];
    const float* gn = (const float*)d_in[9];
    const float* bn = (const float*)d_in[10];
    const float* Wq = (const float*)d_in[11];
    const float* bq = (const float*)d_in[12];
    const float* Wk = (const float*)d_in[13];
    const float* bk = (const float*)d_in[14];
    const float* Wv = (const float*)d_in[15];
    const float* bv = (const float*)d_in[16];
    const float* Wo = (const float*)d_in[17];
    const float* bo = (const float*)d_in[18];
    const float* ga = (const float*)d_in[19];
    const float* ba = (const float*)d_in[20];
    const float* W1 = (const float*)d_in[21];
    const float* b1 = (const float*)d_in[22];
    const float* g1 = (const float*)d_in[23];
    const float* be1 = (const float*)d_in[24];
    const float* W2 = (const float*)d_in[25];
    const float* b2 = (const float*)d_in[26];
    const float* W3 = (const float*)d_in[27];
    const float* b3 = (const float*)d_in[28];
    float* out = (float*)d_out;

    const long NF = (long)N_NODES * 128;
    unsigned char* wsb = (unsigned char*)d_ws;
    const size_t MB = 1 << 20;
    unsigned short* h16 = (unsigned short*)(wsb);             // 8MB
    unsigned short* hw16 = (unsigned short*)(wsb + 8 * MB);   // 8MB
    unsigned short* qkv16 = (unsigned short*)(wsb + 16 * MB); // 24MB
    unsigned short* o16 = (unsigned short*)(wsb + 40 * MB);   // 8MB
    unsigned short* hg16 = (unsigned short*)(wsb + 48 * MB);  // 8MB
    unsigned short* Wpk = (unsigned short*)(wsb + 56 * MB);   // 224KB
    int* srcs = (int*)(wsb + 57 * MB);                        // 16MB (256 x BSTRIDE)
    int* packed = (int*)(wsb + 73 * MB);                      // 16MB (256 x BSTRIDE)
    int* row_ptr = (int*)(wsb + 89 * MB);                     // 128KB
    int* row_end = (int*)(wsb + 90 * MB);                     // 128KB
    float* dis = (float*)(wsb + 91 * MB);                     // 128KB
    float* bT = (float*)(wsb + 92 * MB);                      // 1.5KB
    float* pooled = (float*)(wsb + 92 * MB + 4096);           // 192KB
    int* bucket_fill = (int*)(wsb + 93 * MB);                 // 256 ints

    const int* e_src = ei;
    const int* e_dst = ei + E_EDGES;

    hipMemsetAsync(bucket_fill, 0, 256 * sizeof(int), stream);
    prep_weights<<<dim3(64, 7), 256, 0, stream>>>(Wc, Wq, Wk, Wv, Wo, bq, bk, bv, Wpk, bT);
    bucket_scatter<<<E_EDGES / CHUNK, 256, 0, stream>>>(e_src, e_dst, bucket_fill, packed);
    csr_build<<<256, 256, 0, stream>>>(bucket_fill, packed, srcs, row_ptr, row_end, dis);

    input_proj<<<N_NODES, 128, 0, stream>>>(x, W_in, b_in, g_in, be_in, h16);

    for (int i = 0; i < 3; i++) {
        gemm_mfma<0><<<N_NODES / 64, 256, 0, stream>>>(h16, Wpk + i * 16384, nullptr, nullptr,
                                                       nullptr, nullptr, hw16);
        gcn_agg<<<N_NODES / 4, 256, 0, stream>>>(hw16, row_ptr, row_end, srcs, dis, bc + i * 128,
                                                 gn + i * 128, bn + i * 128, h16, i > 0);
    }

    gemm_qkv<<<dim3(N_NODES / 64, 3), 256, 0, stream>>>(h16, Wpk, bT, qkv16);

    attention<<<dim3(G_GRAPHS, NH), 256, 0, stream>>>(qkv16, qkv16 + NF, qkv16 + 2 * NF, o16);

    gemm_mfma<2><<<N_NODES / 64, 256, 0, stream>>>(o16, Wpk + 6 * 16384, bo, h16, ga, ba, hg16);

    pool_kernel<<<G_GRAPHS, 256, 0, stream>>>(hg16, pooled);
    classifier<<<G_GRAPHS, 128, 0, stream>>>(pooled, W1, b1, g1, be1, W2, b2, W3, b3, out);
}